// Round 13
// baseline (442.537 us; speedup 1.0000x reference)
//
#include <hip/hip_runtime.h>
#include <math.h>

// Problem constants
#define BB 4
#define TT 2048
#define DD 1024
#define HH 4
#define DK 256
#define DV 256
#define RR 8192
#define CHK 64
#define NCHK 32
#define SS ((size_t)RR * DD)

typedef __bf16 bf16x8 __attribute__((ext_vector_type(8)));
typedef float f32x4 __attribute__((ext_vector_type(4)));

static __device__ inline unsigned short f2bf(float f) {
  unsigned int u = __float_as_uint(f);
  unsigned int r = (u + 0x7fffu + ((u >> 16) & 1u)) >> 16;
  return (unsigned short)r;
}
static __device__ inline float bf2f(unsigned short h) {
  return __uint_as_float(((unsigned int)h) << 16);
}

// async global->LDS, 16B per lane; dest = wave-uniform base + lane*16
static __device__ __forceinline__ void gload16(const unsigned short* g,
                                               unsigned short* l) {
  __builtin_amdgcn_global_load_lds(
      (const __attribute__((address_space(1))) void*)g,
      (__attribute__((address_space(3))) void*)l, 16, 0, 0);
}

// ---------------------------------------------------------------------------
// LayerNorm: one block (256 thr) per row of D=1024. f32 in -> bf16 out.
// ---------------------------------------------------------------------------
__global__ __launch_bounds__(256) void ln_kernel(const float* __restrict__ x,
                                                 const float* __restrict__ w,
                                                 const float* __restrict__ b,
                                                 unsigned short* __restrict__ yb) {
  int row = blockIdx.x;
  const float* xr = x + (size_t)row * DD;
  unsigned short* ybr = yb + (size_t)row * DD;
  int tid = threadIdx.x;

  float4 v = ((const float4*)xr)[tid];
  float s = v.x + v.y + v.z + v.w;
  float ss = v.x * v.x + v.y * v.y + v.z * v.z + v.w * v.w;
#pragma unroll
  for (int o = 32; o > 0; o >>= 1) {
    s += __shfl_down(s, o);
    ss += __shfl_down(ss, o);
  }
  __shared__ float ls[4], lss[4];
  int wid = tid >> 6;
  if ((tid & 63) == 0) { ls[wid] = s; lss[wid] = ss; }
  __syncthreads();
  float sum = ls[0] + ls[1] + ls[2] + ls[3];
  float sumsq = lss[0] + lss[1] + lss[2] + lss[3];
  float mu = sum * (1.0f / DD);
  float var = sumsq * (1.0f / DD) - mu * mu;
  float rs = rsqrtf(var + 1e-5f);

  float4 wv = ((const float4*)w)[tid];
  float4 bv = ((const float4*)b)[tid];
  ushort4 ob;
  ob.x = f2bf((v.x - mu) * rs * wv.x + bv.x);
  ob.y = f2bf((v.y - mu) * rs * wv.y + bv.y);
  ob.z = f2bf((v.z - mu) * rs * wv.z + bv.z);
  ob.w = f2bf((v.w - mu) * rs * wv.w + bv.w);
  ((ushort4*)ybr)[tid] = ob;
}

// ---------------------------------------------------------------------------
// Weight transpose + cast: W [K,N] f32 -> Wt [N,K] bf16
// ---------------------------------------------------------------------------
__global__ __launch_bounds__(256) void transpose_cast(const float* __restrict__ W,
                                                      unsigned short* __restrict__ Wt,
                                                      int K, int N) {
  __shared__ float t[32][33];
  int k0 = blockIdx.y * 32, n0 = blockIdx.x * 32;
  int tid = threadIdx.x;
  int tx = tid & 31, ty = tid >> 5;  // ty 0..7
#pragma unroll
  for (int i = 0; i < 4; ++i)
    t[ty + i * 8][tx] = W[(size_t)(k0 + ty + i * 8) * N + n0 + tx];
  __syncthreads();
#pragma unroll
  for (int i = 0; i < 4; ++i)
    Wt[(size_t)(n0 + ty + i * 8) * K + k0 + tx] = f2bf(t[tx][ty + i * 8]);
}

// batched 1024x1024 transpose (5 matrices in one launch)
struct P5 {
  const float* w[5];
  unsigned short* o[5];
};
__global__ __launch_bounds__(256) void transpose5(P5 p) {
  __shared__ float t[32][33];
  int z = blockIdx.z;
  const float* W = p.w[z];
  unsigned short* Wt = p.o[z];
  int k0 = blockIdx.y * 32, n0 = blockIdx.x * 32;
  int tid = threadIdx.x;
  int tx = tid & 31, ty = tid >> 5;
#pragma unroll
  for (int i = 0; i < 4; ++i)
    t[ty + i * 8][tx] = W[(size_t)(k0 + ty + i * 8) * 1024 + n0 + tx];
  __syncthreads();
#pragma unroll
  for (int i = 0; i < 4; ++i)
    Wt[(size_t)(n0 + ty + i * 8) * 1024 + k0 + tx] = f2bf(t[tx][ty + i * 8]);
}

// ---------------------------------------------------------------------------
// bf16 MFMA GEMM: C[M,N] = A[M,K] @ Bt[N,K]^T  (+epilogue)
// 128x128 tile, BK=32, double-buffered global_load_lds staging (16KB total),
// XOR swizzle gs = pos ^ ((row>>2)&3): combined with row parity (64B rows ->
// bank half) this maps 16 frag rows 2-per-(half,pos) class = free 2-way.
// EPI: 0 none, 2 +bias,(leaky)^2, 3 +res, 4 +bias+res,
//      5 proj fan-out: write bf16 to Cv[(n>>10)*SS + m*1024 + (n&1023)]
// ---------------------------------------------------------------------------
template <int EPI, int OUTBF>
__global__ __launch_bounds__(256) void gemm_bf16(
    const unsigned short* __restrict__ A,   // [M,K] bf16
    const unsigned short* __restrict__ Bt,  // [N,K] bf16
    const float* __restrict__ bias, const float* __restrict__ Res,
    void* __restrict__ Cv, int M, int N, int K) {
  __shared__ unsigned short As[2][128 * 32];  // [buf][row][32 bf16] = 8KB
  __shared__ unsigned short Bs[2][128 * 32];
  int tid = threadIdx.x;
  // XCD-aware swizzle (nwg % 8 == 0)
  int nwg = gridDim.x * gridDim.y;
  int wg = blockIdx.y * gridDim.x + blockIdx.x;
  int cpx = nwg >> 3;
  wg = (wg & 7) * cpx + (wg >> 3);
  int m0 = (wg / gridDim.x) * 128, n0 = (wg % gridDim.x) * 128;
  int lane = tid & 63;
  int w64 = tid & 192;  // wave * 64
  int wid = tid >> 6;
  int wm = (wid >> 1) * 64, wn = (wid & 1) * 64;
  int fr = lane & 15, fq = lane >> 4;

  f32x4 acc[4][4] = {};

  auto STAGE = [&](int buf, int k0) {
#pragma unroll
    for (int j = 0; j < 2; ++j) {
      int gl = j * 256 + tid;                 // granule 0..511
      int row = gl >> 2;                      // 0..127
      int gs = (gl & 3) ^ ((row >> 2) & 3);   // inverse-swizzled source granule
      gload16(&A[(size_t)(m0 + row) * K + k0 + gs * 8],
              &As[buf][(size_t)(j * 256 + w64) * 8]);
      gload16(&Bt[(size_t)(n0 + row) * K + k0 + gs * 8],
              &Bs[buf][(size_t)(j * 256 + w64) * 8]);
    }
  };

  STAGE(0, 0);
  asm volatile("s_waitcnt vmcnt(0)");
  __syncthreads();

  int cur = 0;
  for (int k0 = 0; k0 < K; k0 += 32) {
    if (k0 + 32 < K) STAGE(cur ^ 1, k0 + 32);  // prefetch next tile

    bf16x8 af[4], bv[4];
#pragma unroll
    for (int i = 0; i < 4; ++i) {
      int ra = wm + i * 16 + fr;
      af[i] = *(const bf16x8*)&As[cur][ra * 32 + ((fq ^ ((ra >> 2) & 3)) * 8)];
      int rb = wn + i * 16 + fr;
      bv[i] = *(const bf16x8*)&Bs[cur][rb * 32 + ((fq ^ ((rb >> 2) & 3)) * 8)];
    }
#pragma unroll
    for (int i = 0; i < 4; ++i)
#pragma unroll
      for (int jj = 0; jj < 4; ++jj)
        acc[i][jj] = __builtin_amdgcn_mfma_f32_16x16x32_bf16(af[i], bv[jj],
                                                             acc[i][jj], 0, 0, 0);
    __syncthreads();  // drains vmcnt -> prefetched tile visible; buffers safe
    cur ^= 1;
  }

  // epilogue: C/D layout col=lane&15, row=(lane>>4)*4+r
  int col = lane & 15;
  int rbase = (lane >> 4) * 4;
#pragma unroll
  for (int i = 0; i < 4; ++i) {
#pragma unroll
    for (int j = 0; j < 4; ++j) {
      int n = n0 + wn + j * 16 + col;
      float bvv = (EPI == 2 || EPI == 4) ? bias[n] : 0.0f;
#pragma unroll
      for (int r = 0; r < 4; ++r) {
        int m = m0 + wm + i * 16 + rbase + r;
        float vv = acc[i][j][r] + bvv;
        if (EPI == 2) {
          float t = vv > 0.0f ? vv : 0.01f * vv;
          vv = t * t;
        }
        if (EPI == 3 || EPI == 4) vv += Res[(size_t)m * N + n];
        if (EPI == 5) {
          ((unsigned short*)Cv)[(size_t)(n >> 10) * SS + (size_t)m * 1024 +
                                (n & 1023)] = f2bf(vv);
        } else if (OUTBF) {
          ((unsigned short*)Cv)[(size_t)m * N + n] = f2bf(vv);
        } else {
          ((float*)Cv)[(size_t)m * N + n] = vv;
        }
      }
    }
  }
}

// ---------------------------------------------------------------------------
// Low-rank forget gate -> LOG gate gk = log_sigmoid(z)/16
// 16 rows per block; xn + Wgk1(bf16) staged in LDS; Wgk2 amortized 16x via L2.
// ---------------------------------------------------------------------------
__global__ __launch_bounds__(256) void gk_kernel(const unsigned short* __restrict__ xn,
                                                 const float* __restrict__ Wgk1,
                                                 const float* __restrict__ Wgk2,
                                                 const float* __restrict__ bgk2,
                                                 unsigned short* __restrict__ gk) {
  __shared__ unsigned short Xs[16 * 1024];  // 32KB: xn rows, later out tile
  __shared__ unsigned short W1s[1024 * 16]; // 32KB: Wgk1 bf16
  __shared__ float Ts[16][16];
  int r0 = blockIdx.x * 16;
  int tid = threadIdx.x;

#pragma unroll
  for (int i = 0; i < 16; ++i) {
    int idx = tid + i * 256;
    ((ushort4*)Xs)[idx] = ((const ushort4*)(xn + (size_t)r0 * 1024))[idx];
  }
#pragma unroll
  for (int i = 0; i < 16; ++i) {
    int idx = tid + i * 256;
    float4 w = ((const float4*)Wgk1)[idx];
    ushort4 hh;
    hh.x = f2bf(w.x); hh.y = f2bf(w.y); hh.z = f2bf(w.z); hh.w = f2bf(w.w);
    ((ushort4*)W1s)[idx] = hh;
  }
  __syncthreads();

  {
    int r = tid >> 4, part = tid & 15;
    float t16[16];
#pragma unroll
    for (int j = 0; j < 16; ++j) t16[j] = 0.0f;
    for (int dd = 0; dd < 64; ++dd) {
      int d = dd * 16 + part;
      float xv = bf2f(Xs[r * 1024 + d]);
      const ushort4* wr = (const ushort4*)&W1s[d * 16];
#pragma unroll
      for (int q4 = 0; q4 < 4; ++q4) {
        ushort4 w = wr[q4];
        t16[q4 * 4 + 0] += xv * bf2f(w.x);
        t16[q4 * 4 + 1] += xv * bf2f(w.y);
        t16[q4 * 4 + 2] += xv * bf2f(w.z);
        t16[q4 * 4 + 3] += xv * bf2f(w.w);
      }
    }
#pragma unroll
    for (int j = 0; j < 16; ++j) {
      float s = t16[j];
      s += __shfl_xor(s, 1);
      s += __shfl_xor(s, 2);
      s += __shfl_xor(s, 4);
      s += __shfl_xor(s, 8);
      t16[j] = s;
    }
    if (part == 0) {
#pragma unroll
      for (int j = 0; j < 16; ++j) Ts[r][j] = t16[j];
    }
  }
  __syncthreads();

  {
    float w2[16][4];
#pragma unroll
    for (int j = 0; j < 16; ++j) {
      float4 wv = *(const float4*)&Wgk2[(size_t)j * 1024 + tid * 4];
      w2[j][0] = wv.x; w2[j][1] = wv.y; w2[j][2] = wv.z; w2[j][3] = wv.w;
    }
    float4 bv = *(const float4*)&bgk2[tid * 4];
    float bb[4] = {bv.x, bv.y, bv.z, bv.w};
#pragma unroll
    for (int r = 0; r < 16; ++r) {
      ushort4 outv;
      unsigned short* op = (unsigned short*)&outv;
#pragma unroll
      for (int jj = 0; jj < 4; ++jj) {
        float z = bb[jj];
#pragma unroll
        for (int j = 0; j < 16; ++j) z += Ts[r][j] * w2[j][jj];
        float lsg = fminf(z, 0.0f) - log1pf(expf(-fabsf(z)));
        op[jj] = f2bf(lsg * (1.0f / 16.0f));
      }
      *(ushort4*)&Xs[r * 1024 + tid * 4] = outv;
    }
  }
  __syncthreads();
#pragma unroll
  for (int i = 0; i < 16; ++i) {
    int idx = tid + i * 256;
    ((ushort4*)(gk + (size_t)r0 * 1024))[idx] = ((const ushort4*)Xs)[idx];
  }
}

// ---------------------------------------------------------------------------
// gate_chunk: per (b,h,chunk) block, 256 thr (one dk col each).
// ---------------------------------------------------------------------------
__global__ __launch_bounds__(256) void gate_chunk(const unsigned short* __restrict__ gk,
                                                  unsigned short* __restrict__ q,
                                                  unsigned short* __restrict__ k,
                                                  float* __restrict__ ebC) {
  int bid = blockIdx.x;
  int c = bid & 31;
  int h = (bid >> 5) & 3;
  int b = bid >> 7;
  int tid = threadIdx.x;
  size_t base = ((size_t)b * TT + c * CHK) * 1024 + h * 256 + tid;

  float cums[64];
#pragma unroll
  for (int t = 0; t < 64; ++t) cums[t] = bf2f(gk[base + (size_t)t * 1024]);
  float cum = 0.0f;
#pragma unroll
  for (int t = 0; t < 64; ++t) {
    cum += cums[t];
    cums[t] = cum;
  }
  ebC[((b * 4 + h) * NCHK + c) * 256 + tid] = expf(cum);

  const float scale = 0.0625f;
#pragma unroll
  for (int t = 0; t < 64; ++t) {
    size_t a = base + (size_t)t * 1024;
    q[a] = f2bf(bf2f(q[a]) * expf(cums[t]) * scale);
    k[a] = f2bf(bf2f(k[a]) * expf(-cums[t]));
  }
}

// ---------------------------------------------------------------------------
// trans_kernel: [B*T, H*256] slice -> T-major [bh][256][2048]; WITHE folds ebC
// ---------------------------------------------------------------------------
template <int WITHE>
__global__ __launch_bounds__(256) void trans_kernel(const unsigned short* __restrict__ in,
                                                    const float* __restrict__ ebC,
                                                    unsigned short* __restrict__ outT) {
  __shared__ unsigned short T[64][68];
  int bid = blockIdx.x;
  int dkt = bid & 3;
  int ct = (bid >> 2) & 31;
  int bh = bid >> 7;
  int b = bh >> 2, h = bh & 3;
  int tid = threadIdx.x;
  int r = tid >> 4;
  int c4 = (tid & 15) * 4;
  size_t srcbase = ((size_t)b * TT + ct * 64) * 1024 + h * 256 + dkt * 64;
#pragma unroll
  for (int i = 0; i < 4; ++i)
    *(ushort4*)&T[r + i * 16][c4] =
        *(const ushort4*)&in[srcbase + (size_t)(r + i * 16) * 1024 + c4];
  __syncthreads();
  size_t outbase = (size_t)bh * 524288 + (size_t)(dkt * 64) * 2048 + ct * 64;
  const float* ep = ebC + ((size_t)bh * 32 + ct) * 256 + dkt * 64;
#pragma unroll
  for (int i = 0; i < 4; ++i) {
    int dkl = r + i * 16;
    float e = WITHE ? ep[dkl] : 1.0f;
    ushort4 o;
    o.x = f2bf(bf2f(T[c4 + 0][dkl]) * e);
    o.y = f2bf(bf2f(T[c4 + 1][dkl]) * e);
    o.z = f2bf(bf2f(T[c4 + 2][dkl]) * e);
    o.w = f2bf(bf2f(T[c4 + 3][dkl]) * e);
    *(ushort4*)&outT[outbase + (size_t)dkl * 2048 + c4] = o;
  }
}

// ---------------------------------------------------------------------------
// ustate_kernel: fuses u_gemm + hscan. grid = 16bh x 16 tiles (4dv x 4dk),
// 256 thr (4 waves). Per chunk c: reg-load c+1 early (T14); write H_c=state;
// U_c tile via MFMA from LDS[c&1]; state = e*state + U; barrier; ds_write.
// ---------------------------------------------------------------------------
__global__ __launch_bounds__(256) void ustate_kernel(
    const unsigned short* __restrict__ khatT, const unsigned short* __restrict__ vT,
    const float* __restrict__ ebC, unsigned short* __restrict__ HT) {
  __shared__ unsigned short Vs[2][64 * 72];
  __shared__ unsigned short Ks[2][64 * 72];
  int bid = blockIdx.x;
  int tile = bid & 15;
  int bh = bid >> 4;
  int dv0 = (tile >> 2) * 64, dk0 = (tile & 3) * 64;
  const unsigned short* Vb = vT + (size_t)bh * 524288 + (size_t)dv0 * 2048;
  const unsigned short* Kb = khatT + (size_t)bh * 524288 + (size_t)dk0 * 2048;
  int tid = threadIdx.x;
  int lane = tid & 63;
  int w = tid >> 6;
  int fr = lane & 15, fq = lane >> 4;

  bf16x8 vr[2], kr[2], nvr[2], nkr[2];
  auto LOADR = [&](int c, bf16x8 vv[2], bf16x8 kk[2]) {
#pragma unroll
    for (int j = 0; j < 2; ++j) {
      int g = j * 256 + tid;
      int row = g >> 3, gc = g & 7;
      vv[j] = *(const bf16x8*)&Vb[(size_t)row * 2048 + c * 64 + gc * 8];
      kk[j] = *(const bf16x8*)&Kb[(size_t)row * 2048 + c * 64 + gc * 8];
    }
  };
  auto WLDS = [&](int buf, bf16x8 vv[2], bf16x8 kk[2]) {
#pragma unroll
    for (int j = 0; j < 2; ++j) {
      int g = j * 256 + tid;
      int row = g >> 3, gc = g & 7;
      *(bf16x8*)&Vs[buf][row * 72 + gc * 8] = vv[j];
      *(bf16x8*)&Ks[buf][row * 72 + gc * 8] = kk[j];
    }
  };

  f32x4 st[4] = {};

  LOADR(0, vr, kr);
  WLDS(0, vr, kr);
  __syncthreads();

  for (int c = 0; c < NCHK; ++c) {
    int cur = c & 1;
    if (c + 1 < NCHK) LOADR(c + 1, nvr, nkr);

    size_t hb = ((size_t)(bh * NCHK + c)) * 65536;
#pragma unroll
    for (int nj = 0; nj < 4; ++nj) {
#pragma unroll
      for (int r = 0; r < 4; ++r) {
        int dv = dv0 + w * 16 + fq * 4 + r;
        int dk = dk0 + nj * 16 + fr;
        HT[hb + (size_t)dv * 256 + dk] = f2bf(st[nj][r]);
      }
    }

    f32x4 uacc[4] = {};
#pragma unroll
    for (int ks = 0; ks < 2; ++ks) {
      bf16x8 av = *(const bf16x8*)&Vs[cur][(w * 16 + fr) * 72 + ks * 32 + fq * 8];
#pragma unroll
      for (int nj = 0; nj < 4; ++nj) {
        bf16x8 bk = *(const bf16x8*)&Ks[cur][(nj * 16 + fr) * 72 + ks * 32 + fq * 8];
        uacc[nj] = __builtin_amdgcn_mfma_f32_16x16x32_bf16(av, bk, uacc[nj], 0, 0, 0);
      }
    }

    const float* ec = ebC + ((size_t)bh * NCHK + c) * 256 + dk0;
#pragma unroll
    for (int nj = 0; nj < 4; ++nj) {
      float e = ec[nj * 16 + fr];
      st[nj] = e * st[nj] + uacc[nj];
    }

    __syncthreads();
    if (c + 1 < NCHK) {
      WLDS(cur ^ 1, nvr, nkr);
      __syncthreads();
    }
  }
}

// ---------------------------------------------------------------------------
// attn_fused: per (bh,c), 4 waves. intra + inter + gated RMSNorm -> og bf16
// ---------------------------------------------------------------------------
__global__ __launch_bounds__(256) void attn_fused(
    const unsigned short* __restrict__ qt, const unsigned short* __restrict__ kt,
    const unsigned short* __restrict__ vT, const unsigned short* __restrict__ HT,
    const unsigned short* __restrict__ gp, const float* __restrict__ rw,
    unsigned short* __restrict__ og) {
  __shared__ unsigned short Qs[64 * 264];
  __shared__ unsigned short KVH[256 * 72];
  __shared__ unsigned short Sb[64 * 64];
  __shared__ float red[64][4];

  int bid = blockIdx.x;
  int c = bid & 31;
  int bh = bid >> 5;
  int b = bh >> 2, h = bh & 3;
  size_t rowbase = ((size_t)b * TT + c * 64) * 1024 + h * 256;
  size_t vtbase = (size_t)bh * 524288 + c * 64;
  size_t htbase = ((size_t)(bh * 32 + c)) * 65536;
  int tid = threadIdx.x;
  int lane = tid & 63;
  int w = tid >> 6;
  int fr = lane & 15, fq = lane >> 4;

#pragma unroll
  for (int i = 0; i < 8; ++i) {
    int gg = tid + i * 256;
    int row = gg >> 5, gc = gg & 31;
    *(bf16x8*)&Qs[row * 264 + gc * 8] =
        *(const bf16x8*)&qt[rowbase + (size_t)row * 1024 + gc * 8];
    *(bf16x8*)&KVH[row * 264 + gc * 8] =
        *(const bf16x8*)&kt[rowbase + (size_t)row * 1024 + gc * 8];
  }
  __syncthreads();

  {
    f32x4 accs[4] = {};
#pragma unroll
    for (int ks = 0; ks < 8; ++ks) {
      bf16x8 af = *(const bf16x8*)&Qs[(w * 16 + fr) * 264 + ks * 32 + fq * 8];
#pragma unroll
      for (int si = 0; si < 4; ++si) {
        bf16x8 bf_ = *(const bf16x8*)&KVH[(si * 16 + fr) * 264 + ks * 32 + fq * 8];
        accs[si] = __builtin_amdgcn_mfma_f32_16x16x32_bf16(af, bf_, accs[si], 0, 0, 0);
      }
    }
#pragma unroll
    for (int si = 0; si < 4; ++si) {
#pragma unroll
      for (int r = 0; r < 4; ++r) {
        int t = w * 16 + fq * 4 + r;
        int s = si * 16 + fr;
        float val = (s <= t) ? accs[si][r] : 0.0f;
        Sb[t * 64 + (((s >> 3) ^ (t & 7)) * 8) + (s & 7)] = f2bf(val);
      }
    }
  }
  __syncthreads();

#pragma unroll
  for (int i = 0; i < 8; ++i) {
    int gg = tid + i * 256;
    int dv = gg >> 3, gc = gg & 7;
    *(bf16x8*)&KVH[dv * 72 + gc * 8] =
        *(const bf16x8*)&vT[vtbase + (size_t)dv * 2048 + gc * 8];
  }
  __syncthreads();

  int dv0 = w * 64;
  f32x4 acc[4][4] = {};

#pragma unroll
  for (int ks = 0; ks < 2; ++ks) {
    bf16x8 af[4], bv[4];
#pragma unroll
    for (int ti = 0; ti < 4; ++ti) {
      int t = ti * 16 + fr;
      af[ti] = *(const bf16x8*)&Sb[t * 64 + (((ks * 4 + fq) ^ (t & 7)) * 8)];
    }
#pragma unroll
    for (int nj = 0; nj < 4; ++nj)
      bv[nj] = *(const bf16x8*)&KVH[(dv0 + nj * 16 + fr) * 72 + ks * 32 + fq * 8];
#pragma unroll
    for (int ti = 0; ti < 4; ++ti)
#pragma unroll
      for (int nj = 0; nj < 4; ++nj)
        acc[ti][nj] = __builtin_amdgcn_mfma_f32_16x16x32_bf16(af[ti], bv[nj],
                                                              acc[ti][nj], 0, 0, 0);
  }

  for (int k4 = 0; k4 < 4; ++k4) {
    __syncthreads();
#pragma unroll
    for (int i = 0; i < 8; ++i) {
      int gg = tid + i * 256;
      int dv = gg >> 3, gc = gg & 7;
      *(bf16x8*)&KVH[dv * 72 + gc * 8] =
          *(const bf16x8*)&HT[htbase + (size_t)dv * 256 + k4 * 64 + gc * 8];
    }
    __syncthreads();
#pragma unroll
    for (int ks = 0; ks < 2; ++ks) {
      bf16x8 af[4], bv[4];
#pragma unroll
      for (int ti = 0; ti < 4; ++ti)
        af[ti] = *(const bf16x8*)&Qs[(ti * 16 + fr) * 264 + k4 * 64 + ks * 32 + fq * 8];
#pragma unroll
      for (int nj = 0; nj < 4; ++nj)
        bv[nj] = *(const bf16x8*)&KVH[(dv0 + nj * 16 + fr) * 72 + ks * 32 + fq * 8];
#pragma unroll
      for (int ti = 0; ti < 4; ++ti)
#pragma unroll
        for (int nj = 0; nj < 4; ++nj)
          acc[ti][nj] = __builtin_amdgcn_mfma_f32_16x16x32_bf16(af[ti], bv[nj],
                                                                acc[ti][nj], 0, 0, 0);
    }
  }

  float rstd[4][4];
#pragma unroll
  for (int ti = 0; ti < 4; ++ti) {
#pragma unroll
    for (int r = 0; r < 4; ++r) {
      float s = 0.0f;
#pragma unroll
      for (int nj = 0; nj < 4; ++nj) {
        float v = acc[ti][nj][r];
        s += v * v;
      }
      s += __shfl_xor(s, 1);
      s += __shfl_xor(s, 2);
      s += __shfl_xor(s, 4);
      s += __shfl_xor(s, 8);
      rstd[ti][r] = s;
    }
  }
  if (fr == 0) {
#pragma unroll
    for (int ti = 0; ti < 4; ++ti)
#pragma unroll
      for (int r = 0; r < 4; ++r)
        red[ti * 16 + fq * 4 + r][w] = rstd[ti][r];
  }
  __syncthreads();
#pragma unroll
  for (int ti = 0; ti < 4; ++ti) {
#pragma unroll
    for (int r = 0; r < 4; ++r) {
      int t = ti * 16 + fq * 4 + r;
      float tot = red[t][0] + red[t][1] + red[t][2] + red[t][3];
      rstd[ti][r] = rsqrtf(tot * (1.0f / 256.0f) + 1e-5f);
    }
  }
#pragma unroll
  for (int ti = 0; ti < 4; ++ti) {
#pragma unroll
    for (int nj = 0; nj < 4; ++nj) {
      int dv = dv0 + nj * 16 + fr;
      float rwv = rw[dv];
#pragma unroll
      for (int r = 0; r < 4; ++r) {
        int t = ti * 16 + fq * 4 + r;
        float gv = bf2f(gp[rowbase + (size_t)t * 1024 + dv]);
        float sw = gv / (1.0f + expf(-gv));
        og[rowbase + (size_t)t * 1024 + dv] =
            f2bf(acc[ti][nj][r] * rstd[ti][r] * rwv * sw);
      }
    }
  }
}

// ---------------------------------------------------------------------------
extern "C" void kernel_launch(void* const* d_in, const int* in_sizes, int n_in,
                              void* d_out, int out_size, void* d_ws,
                              size_t ws_size, hipStream_t stream) {
  const float* x = (const float*)d_in[0];
  const float* ln1_w = (const float*)d_in[1];
  const float* ln1_b = (const float*)d_in[2];
  const float* Wq = (const float*)d_in[3];
  const float* Wk = (const float*)d_in[4];
  const float* Wv = (const float*)d_in[5];
  const float* Wg = (const float*)d_in[6];
  const float* Wgk1 = (const float*)d_in[7];
  const float* Wgk2 = (const float*)d_in[8];
  const float* bgk2 = (const float*)d_in[9];
  const float* rms_w = (const float*)d_in[10];
  const float* Wo = (const float*)d_in[11];
  const float* ln2_w = (const float*)d_in[12];
  const float* ln2_b = (const float*)d_in[13];
  const float* W1 = (const float*)d_in[14];
  const float* b1 = (const float*)d_in[15];
  const float* W2 = (const float*)d_in[16];
  const float* b2 = (const float*)d_in[17];
  float* out = (float*)d_out;

  const size_t S = SS;
  unsigned short* actb = (unsigned short*)d_ws;  // xn -> vT -> xn2
  unsigned short* qb = actb + S;
  unsigned short* kb = qb + S;
  unsigned short* vb = kb + S;
  unsigned short* gb = vb + S;
  unsigned short* gkb = gb + S;
  unsigned short* ogb = gkb + S;
  unsigned short* UH = ogb + 2 * S;              // HT (written by ustate)
  float* ebC = (float*)(UH + 4 * S);
  unsigned short* Wqkvgt = (unsigned short*)(ebC + 131072);
  unsigned short* Wot = Wqkvgt + 4194304;
  unsigned short* W1t = Wot + 1048576;
  unsigned short* W2t = W1t + 3145728;
  unsigned short* khatT = gkb;
  unsigned short* vT = actb;
  float* x1 = (float*)kb;
  unsigned short* hb = UH;

  dim3 blk(256);

  P5 p5;
  p5.w[0] = Wq;  p5.o[0] = Wqkvgt;
  p5.w[1] = Wk;  p5.o[1] = Wqkvgt + 1048576;
  p5.w[2] = Wv;  p5.o[2] = Wqkvgt + 2097152;
  p5.w[3] = Wg;  p5.o[3] = Wqkvgt + 3145728;
  p5.w[4] = Wo;  p5.o[4] = Wot;
  transpose5<<<dim3(32, 32, 5), blk, 0, stream>>>(p5);
  transpose_cast<<<dim3(96, 32), blk, 0, stream>>>(W1, W1t, 1024, 3072);
  transpose_cast<<<dim3(32, 96), blk, 0, stream>>>(W2, W2t, 3072, 1024);

  // 1. xn = LN(x)
  ln_kernel<<<RR, blk, 0, stream>>>(x, ln1_w, ln1_b, actb);

  // 2. merged q|k|v|g projection
  dim3 g4096(4096 / 128, RR / 128);
  gemm_bf16<5, 1><<<g4096, blk, 0, stream>>>(actb, Wqkvgt, nullptr, nullptr, qb,
                                             RR, 4096, 1024);

  // 3. gk -> gkb
  gk_kernel<<<RR / 16, blk, 0, stream>>>(actb, Wgk1, Wgk2, bgk2, gkb);

  // 4. gate transforms (in-place q,k), ebC
  gate_chunk<<<BB * HH * NCHK, blk, 0, stream>>>(gkb, qb, kb, ebC);

  // 5. transposes: khatT (ebC folded) over gkb; vT over actb
  trans_kernel<1><<<16 * 32 * 4, blk, 0, stream>>>(kb, ebC, khatT);
  trans_kernel<0><<<16 * 32 * 4, blk, 0, stream>>>(vb, ebC, vT);

  // 6. fused U + scan -> HT (UH region)
  ustate_kernel<<<16 * 16, blk, 0, stream>>>(khatT, vT, ebC, UH);

  // 7. fused intra + inter + gated rmsnorm -> ogb
  attn_fused<<<16 * NCHK, blk, 0, stream>>>(qb, kb, vT, UH, gb, rms_w, ogb);

  // 8. x1 = x + og @ Wo
  dim3 g1024(1024 / 128, RR / 128);
  gemm_bf16<3, 0><<<g1024, blk, 0, stream>>>(ogb, Wot, nullptr, x, x1, RR, 1024, 1024);

  // 9. xn2 = LN(x1) -> actb
  ln_kernel<<<RR, blk, 0, stream>>>(x1, ln2_w, ln2_b, actb);

  // 10. h = (leaky_relu(xn2@W1+b1))^2 -> hb
  dim3 g3072(3072 / 128, RR / 128);
  gemm_bf16<2, 1><<<g3072, blk, 0, stream>>>(actb, W1t, b1, nullptr, hb, RR, 3072, 1024);

  // 11. out = x1 + h @ W2 + b2
  gemm_bf16<4, 0><<<g1024, blk, 0, stream>>>(hb, W2t, b2, x1, out, RR, 1024, 3072);
}

// Round 14
// 412.097 us; speedup vs baseline: 1.0739x; 1.0739x over previous
//
#include <hip/hip_runtime.h>
#include <math.h>

// Problem constants
#define BB 4
#define TT 2048
#define DD 1024
#define HH 4
#define DK 256
#define DV 256
#define RR 8192
#define CHK 64
#define NCHK 32
#define SS ((size_t)RR * DD)

typedef __bf16 bf16x8 __attribute__((ext_vector_type(8)));
typedef float f32x4 __attribute__((ext_vector_type(4)));

static __device__ inline unsigned short f2bf(float f) {
  unsigned int u = __float_as_uint(f);
  unsigned int r = (u + 0x7fffu + ((u >> 16) & 1u)) >> 16;
  return (unsigned short)r;
}
static __device__ inline float bf2f(unsigned short h) {
  return __uint_as_float(((unsigned int)h) << 16);
}

// async global->LDS, 16B per lane; dest = wave-uniform base + lane*16
static __device__ __forceinline__ void gload16(const unsigned short* g,
                                               unsigned short* l) {
  __builtin_amdgcn_global_load_lds(
      (const __attribute__((address_space(1))) void*)g,
      (__attribute__((address_space(3))) void*)l, 16, 0, 0);
}

// ---------------------------------------------------------------------------
// LayerNorm: one block (256 thr) per row of D=1024. f32 in -> bf16 out.
// ---------------------------------------------------------------------------
__global__ __launch_bounds__(256) void ln_kernel(const float* __restrict__ x,
                                                 const float* __restrict__ w,
                                                 const float* __restrict__ b,
                                                 unsigned short* __restrict__ yb) {
  int row = blockIdx.x;
  const float* xr = x + (size_t)row * DD;
  unsigned short* ybr = yb + (size_t)row * DD;
  int tid = threadIdx.x;

  float4 v = ((const float4*)xr)[tid];
  float s = v.x + v.y + v.z + v.w;
  float ss = v.x * v.x + v.y * v.y + v.z * v.z + v.w * v.w;
#pragma unroll
  for (int o = 32; o > 0; o >>= 1) {
    s += __shfl_down(s, o);
    ss += __shfl_down(ss, o);
  }
  __shared__ float ls[4], lss[4];
  int wid = tid >> 6;
  if ((tid & 63) == 0) { ls[wid] = s; lss[wid] = ss; }
  __syncthreads();
  float sum = ls[0] + ls[1] + ls[2] + ls[3];
  float sumsq = lss[0] + lss[1] + lss[2] + lss[3];
  float mu = sum * (1.0f / DD);
  float var = sumsq * (1.0f / DD) - mu * mu;
  float rs = rsqrtf(var + 1e-5f);

  float4 wv = ((const float4*)w)[tid];
  float4 bv = ((const float4*)b)[tid];
  ushort4 ob;
  ob.x = f2bf((v.x - mu) * rs * wv.x + bv.x);
  ob.y = f2bf((v.y - mu) * rs * wv.y + bv.y);
  ob.z = f2bf((v.z - mu) * rs * wv.z + bv.z);
  ob.w = f2bf((v.w - mu) * rs * wv.w + bv.w);
  ((ushort4*)ybr)[tid] = ob;
}

// ---------------------------------------------------------------------------
// Weight transpose + cast: W [K,N] f32 -> Wt [N,K] bf16
// ---------------------------------------------------------------------------
__global__ __launch_bounds__(256) void transpose_cast(const float* __restrict__ W,
                                                      unsigned short* __restrict__ Wt,
                                                      int K, int N) {
  __shared__ float t[32][33];
  int k0 = blockIdx.y * 32, n0 = blockIdx.x * 32;
  int tid = threadIdx.x;
  int tx = tid & 31, ty = tid >> 5;  // ty 0..7
#pragma unroll
  for (int i = 0; i < 4; ++i)
    t[ty + i * 8][tx] = W[(size_t)(k0 + ty + i * 8) * N + n0 + tx];
  __syncthreads();
#pragma unroll
  for (int i = 0; i < 4; ++i)
    Wt[(size_t)(n0 + ty + i * 8) * K + k0 + tx] = f2bf(t[tx][ty + i * 8]);
}

// batched 1024x1024 transpose (5 matrices in one launch)
struct P5 {
  const float* w[5];
  unsigned short* o[5];
};
__global__ __launch_bounds__(256) void transpose5(P5 p) {
  __shared__ float t[32][33];
  int z = blockIdx.z;
  const float* W = p.w[z];
  unsigned short* Wt = p.o[z];
  int k0 = blockIdx.y * 32, n0 = blockIdx.x * 32;
  int tid = threadIdx.x;
  int tx = tid & 31, ty = tid >> 5;
#pragma unroll
  for (int i = 0; i < 4; ++i)
    t[ty + i * 8][tx] = W[(size_t)(k0 + ty + i * 8) * 1024 + n0 + tx];
  __syncthreads();
#pragma unroll
  for (int i = 0; i < 4; ++i)
    Wt[(size_t)(n0 + ty + i * 8) * 1024 + k0 + tx] = f2bf(t[tx][ty + i * 8]);
}

// ---------------------------------------------------------------------------
// bf16 MFMA GEMM: C[M,N] = A[M,K] @ Bt[N,K]^T  (+epilogue)
// 128x128 tile, BK=64, double-buffered global_load_lds staging, XOR-swizzled
// LDS (granule ^= row&7; 128B rows -> full-bank spread, measured 0 conflicts),
// XCD block swizzle. (R10-proven version, 763 TF on the merged proj.)
// EPI: 0 none, 2 +bias,(leaky)^2, 3 +res, 4 +bias+res,
//      5 proj fan-out: write bf16 to Cv[(n>>10)*SS + m*1024 + (n&1023)]
// ---------------------------------------------------------------------------
template <int EPI, int OUTBF>
__global__ __launch_bounds__(256) void gemm_bf16(
    const unsigned short* __restrict__ A,   // [M,K] bf16
    const unsigned short* __restrict__ Bt,  // [N,K] bf16
    const float* __restrict__ bias, const float* __restrict__ Res,
    void* __restrict__ Cv, int M, int N, int K) {
  __shared__ unsigned short As[2][128 * 64];  // [buf][row][64 bf16]
  __shared__ unsigned short Bs[2][128 * 64];
  int tid = threadIdx.x;
  // XCD-aware swizzle (nwg % 8 == 0)
  int nwg = gridDim.x * gridDim.y;
  int wg = blockIdx.y * gridDim.x + blockIdx.x;
  int cpx = nwg >> 3;
  wg = (wg & 7) * cpx + (wg >> 3);
  int m0 = (wg / gridDim.x) * 128, n0 = (wg % gridDim.x) * 128;
  int lane = tid & 63;
  int w64 = tid & 192;  // wave * 64
  int wid = tid >> 6;
  int wm = (wid >> 1) * 64, wn = (wid & 1) * 64;
  int fr = lane & 15, fq = lane >> 4;

  f32x4 acc[4][4] = {};

  auto STAGE = [&](int buf, int k0) {
#pragma unroll
    for (int j = 0; j < 4; ++j) {
      int gl = j * 256 + tid;           // granule 0..1023
      int row = gl >> 3;
      int gs = (gl & 7) ^ (row & 7);    // inverse-swizzled source granule
      gload16(&A[(size_t)(m0 + row) * K + k0 + gs * 8],
              &As[buf][(size_t)(j * 256 + w64) * 8]);
      gload16(&Bt[(size_t)(n0 + row) * K + k0 + gs * 8],
              &Bs[buf][(size_t)(j * 256 + w64) * 8]);
    }
  };

  STAGE(0, 0);
  asm volatile("s_waitcnt vmcnt(0)");
  __syncthreads();

  int cur = 0;
  for (int k0 = 0; k0 < K; k0 += 64) {
    if (k0 + 64 < K) STAGE(cur ^ 1, k0 + 64);  // prefetch next tile

#pragma unroll
    for (int ph = 0; ph < 2; ++ph) {
      bf16x8 af[4], bv[4];
#pragma unroll
      for (int i = 0; i < 4; ++i) {
        int ra = wm + i * 16 + fr;
        af[i] = *(const bf16x8*)&As[cur][ra * 64 + (((ph * 4 + fq) ^ (ra & 7)) * 8)];
        int rb = wn + i * 16 + fr;
        bv[i] = *(const bf16x8*)&Bs[cur][rb * 64 + (((ph * 4 + fq) ^ (rb & 7)) * 8)];
      }
#pragma unroll
      for (int i = 0; i < 4; ++i)
#pragma unroll
        for (int jj = 0; jj < 4; ++jj)
          acc[i][jj] = __builtin_amdgcn_mfma_f32_16x16x32_bf16(af[i], bv[jj],
                                                               acc[i][jj], 0, 0, 0);
    }
    __syncthreads();  // drains vmcnt -> prefetched tile visible; buffers safe
    cur ^= 1;
  }

  // epilogue: C/D layout col=lane&15, row=(lane>>4)*4+r
  int col = lane & 15;
  int rbase = (lane >> 4) * 4;
#pragma unroll
  for (int i = 0; i < 4; ++i) {
#pragma unroll
    for (int j = 0; j < 4; ++j) {
      int n = n0 + wn + j * 16 + col;
      float bvv = (EPI == 2 || EPI == 4) ? bias[n] : 0.0f;
#pragma unroll
      for (int r = 0; r < 4; ++r) {
        int m = m0 + wm + i * 16 + rbase + r;
        float vv = acc[i][j][r] + bvv;
        if (EPI == 2) {
          float t = vv > 0.0f ? vv : 0.01f * vv;
          vv = t * t;
        }
        if (EPI == 3 || EPI == 4) vv += Res[(size_t)m * N + n];
        if (EPI == 5) {
          ((unsigned short*)Cv)[(size_t)(n >> 10) * SS + (size_t)m * 1024 +
                                (n & 1023)] = f2bf(vv);
        } else if (OUTBF) {
          ((unsigned short*)Cv)[(size_t)m * N + n] = f2bf(vv);
        } else {
          ((float*)Cv)[(size_t)m * N + n] = vv;
        }
      }
    }
  }
}

// ---------------------------------------------------------------------------
// Low-rank forget gate -> LOG gate gk = log_sigmoid(z)/16
// 16 rows per block; xn + Wgk1(bf16) staged in LDS; Wgk2 amortized 16x via L2.
// ---------------------------------------------------------------------------
__global__ __launch_bounds__(256) void gk_kernel(const unsigned short* __restrict__ xn,
                                                 const float* __restrict__ Wgk1,
                                                 const float* __restrict__ Wgk2,
                                                 const float* __restrict__ bgk2,
                                                 unsigned short* __restrict__ gk) {
  __shared__ unsigned short Xs[16 * 1024];  // 32KB: xn rows, later out tile
  __shared__ unsigned short W1s[1024 * 16]; // 32KB: Wgk1 bf16
  __shared__ float Ts[16][16];
  int r0 = blockIdx.x * 16;
  int tid = threadIdx.x;

#pragma unroll
  for (int i = 0; i < 16; ++i) {
    int idx = tid + i * 256;
    ((ushort4*)Xs)[idx] = ((const ushort4*)(xn + (size_t)r0 * 1024))[idx];
  }
#pragma unroll
  for (int i = 0; i < 16; ++i) {
    int idx = tid + i * 256;
    float4 w = ((const float4*)Wgk1)[idx];
    ushort4 hh;
    hh.x = f2bf(w.x); hh.y = f2bf(w.y); hh.z = f2bf(w.z); hh.w = f2bf(w.w);
    ((ushort4*)W1s)[idx] = hh;
  }
  __syncthreads();

  {
    int r = tid >> 4, part = tid & 15;
    float t16[16];
#pragma unroll
    for (int j = 0; j < 16; ++j) t16[j] = 0.0f;
    for (int dd = 0; dd < 64; ++dd) {
      int d = dd * 16 + part;
      float xv = bf2f(Xs[r * 1024 + d]);
      const ushort4* wr = (const ushort4*)&W1s[d * 16];
#pragma unroll
      for (int q4 = 0; q4 < 4; ++q4) {
        ushort4 w = wr[q4];
        t16[q4 * 4 + 0] += xv * bf2f(w.x);
        t16[q4 * 4 + 1] += xv * bf2f(w.y);
        t16[q4 * 4 + 2] += xv * bf2f(w.z);
        t16[q4 * 4 + 3] += xv * bf2f(w.w);
      }
    }
#pragma unroll
    for (int j = 0; j < 16; ++j) {
      float s = t16[j];
      s += __shfl_xor(s, 1);
      s += __shfl_xor(s, 2);
      s += __shfl_xor(s, 4);
      s += __shfl_xor(s, 8);
      t16[j] = s;
    }
    if (part == 0) {
#pragma unroll
      for (int j = 0; j < 16; ++j) Ts[r][j] = t16[j];
    }
  }
  __syncthreads();

  {
    float w2[16][4];
#pragma unroll
    for (int j = 0; j < 16; ++j) {
      float4 wv = *(const float4*)&Wgk2[(size_t)j * 1024 + tid * 4];
      w2[j][0] = wv.x; w2[j][1] = wv.y; w2[j][2] = wv.z; w2[j][3] = wv.w;
    }
    float4 bv = *(const float4*)&bgk2[tid * 4];
    float bb[4] = {bv.x, bv.y, bv.z, bv.w};
#pragma unroll
    for (int r = 0; r < 16; ++r) {
      ushort4 outv;
      unsigned short* op = (unsigned short*)&outv;
#pragma unroll
      for (int jj = 0; jj < 4; ++jj) {
        float z = bb[jj];
#pragma unroll
        for (int j = 0; j < 16; ++j) z += Ts[r][j] * w2[j][jj];
        float lsg = fminf(z, 0.0f) - log1pf(expf(-fabsf(z)));
        op[jj] = f2bf(lsg * (1.0f / 16.0f));
      }
      *(ushort4*)&Xs[r * 1024 + tid * 4] = outv;
    }
  }
  __syncthreads();
#pragma unroll
  for (int i = 0; i < 16; ++i) {
    int idx = tid + i * 256;
    ((ushort4*)(gk + (size_t)r0 * 1024))[idx] = ((const ushort4*)Xs)[idx];
  }
}

// ---------------------------------------------------------------------------
// gate_chunk: per (b,h,chunk) block, 256 thr (one dk col each).
// ---------------------------------------------------------------------------
__global__ __launch_bounds__(256) void gate_chunk(const unsigned short* __restrict__ gk,
                                                  unsigned short* __restrict__ q,
                                                  unsigned short* __restrict__ k,
                                                  float* __restrict__ ebC) {
  int bid = blockIdx.x;
  int c = bid & 31;
  int h = (bid >> 5) & 3;
  int b = bid >> 7;
  int tid = threadIdx.x;
  size_t base = ((size_t)b * TT + c * CHK) * 1024 + h * 256 + tid;

  float cums[64];
#pragma unroll
  for (int t = 0; t < 64; ++t) cums[t] = bf2f(gk[base + (size_t)t * 1024]);
  float cum = 0.0f;
#pragma unroll
  for (int t = 0; t < 64; ++t) {
    cum += cums[t];
    cums[t] = cum;
  }
  ebC[((b * 4 + h) * NCHK + c) * 256 + tid] = expf(cum);

  const float scale = 0.0625f;
#pragma unroll
  for (int t = 0; t < 64; ++t) {
    size_t a = base + (size_t)t * 1024;
    q[a] = f2bf(bf2f(q[a]) * expf(cums[t]) * scale);
    k[a] = f2bf(bf2f(k[a]) * expf(-cums[t]));
  }
}

// ---------------------------------------------------------------------------
// trans2: both transposes in one launch. bid < 2048: k~ -> khatT (ebC folded);
// bid >= 2048: v -> vT (no fold). Layout identical to old trans_kernel.
// ---------------------------------------------------------------------------
__global__ __launch_bounds__(256) void trans2(const unsigned short* __restrict__ kin,
                                              const unsigned short* __restrict__ vin,
                                              const float* __restrict__ ebC,
                                              unsigned short* __restrict__ kout,
                                              unsigned short* __restrict__ vout) {
  __shared__ unsigned short T[64][68];
  int bid0 = blockIdx.x;
  int mode = bid0 >> 11;            // 0: khat, 1: v
  int bid = bid0 & 2047;
  const unsigned short* in = mode ? vin : kin;
  unsigned short* outT = mode ? vout : kout;
  int dkt = bid & 3;
  int ct = (bid >> 2) & 31;
  int bh = bid >> 7;
  int b = bh >> 2, h = bh & 3;
  int tid = threadIdx.x;
  int r = tid >> 4;
  int c4 = (tid & 15) * 4;
  size_t srcbase = ((size_t)b * TT + ct * 64) * 1024 + h * 256 + dkt * 64;
#pragma unroll
  for (int i = 0; i < 4; ++i)
    *(ushort4*)&T[r + i * 16][c4] =
        *(const ushort4*)&in[srcbase + (size_t)(r + i * 16) * 1024 + c4];
  __syncthreads();
  size_t outbase = (size_t)bh * 524288 + (size_t)(dkt * 64) * 2048 + ct * 64;
  const float* ep = ebC + ((size_t)bh * 32 + ct) * 256 + dkt * 64;
#pragma unroll
  for (int i = 0; i < 4; ++i) {
    int dkl = r + i * 16;
    float e = mode ? 1.0f : ep[dkl];
    ushort4 o;
    o.x = f2bf(bf2f(T[c4 + 0][dkl]) * e);
    o.y = f2bf(bf2f(T[c4 + 1][dkl]) * e);
    o.z = f2bf(bf2f(T[c4 + 2][dkl]) * e);
    o.w = f2bf(bf2f(T[c4 + 3][dkl]) * e);
    *(ushort4*)&outT[outbase + (size_t)dkl * 2048 + c4] = o;
  }
}

// ---------------------------------------------------------------------------
// ustate_kernel: fuses u_gemm + hscan. grid = 16bh x 16 tiles (4dv x 4dk),
// 256 thr (4 waves). Per chunk c: reg-load c+1 early (T14); write H_c=state;
// U_c tile via MFMA from LDS[c&1]; state = e*state + U; barrier; ds_write.
// ---------------------------------------------------------------------------
__global__ __launch_bounds__(256) void ustate_kernel(
    const unsigned short* __restrict__ khatT, const unsigned short* __restrict__ vT,
    const float* __restrict__ ebC, unsigned short* __restrict__ HT) {
  __shared__ unsigned short Vs[2][64 * 72];
  __shared__ unsigned short Ks[2][64 * 72];
  int bid = blockIdx.x;
  int tile = bid & 15;
  int bh = bid >> 4;
  int dv0 = (tile >> 2) * 64, dk0 = (tile & 3) * 64;
  const unsigned short* Vb = vT + (size_t)bh * 524288 + (size_t)dv0 * 2048;
  const unsigned short* Kb = khatT + (size_t)bh * 524288 + (size_t)dk0 * 2048;
  int tid = threadIdx.x;
  int lane = tid & 63;
  int w = tid >> 6;
  int fr = lane & 15, fq = lane >> 4;

  bf16x8 vr[2], kr[2], nvr[2], nkr[2];
  auto LOADR = [&](int c, bf16x8 vv[2], bf16x8 kk[2]) {
#pragma unroll
    for (int j = 0; j < 2; ++j) {
      int g = j * 256 + tid;
      int row = g >> 3, gc = g & 7;
      vv[j] = *(const bf16x8*)&Vb[(size_t)row * 2048 + c * 64 + gc * 8];
      kk[j] = *(const bf16x8*)&Kb[(size_t)row * 2048 + c * 64 + gc * 8];
    }
  };
  auto WLDS = [&](int buf, bf16x8 vv[2], bf16x8 kk[2]) {
#pragma unroll
    for (int j = 0; j < 2; ++j) {
      int g = j * 256 + tid;
      int row = g >> 3, gc = g & 7;
      *(bf16x8*)&Vs[buf][row * 72 + gc * 8] = vv[j];
      *(bf16x8*)&Ks[buf][row * 72 + gc * 8] = kk[j];
    }
  };

  f32x4 st[4] = {};

  LOADR(0, vr, kr);
  WLDS(0, vr, kr);
  __syncthreads();

  for (int c = 0; c < NCHK; ++c) {
    int cur = c & 1;
    if (c + 1 < NCHK) LOADR(c + 1, nvr, nkr);

    size_t hb = ((size_t)(bh * NCHK + c)) * 65536;
#pragma unroll
    for (int nj = 0; nj < 4; ++nj) {
#pragma unroll
      for (int r = 0; r < 4; ++r) {
        int dv = dv0 + w * 16 + fq * 4 + r;
        int dk = dk0 + nj * 16 + fr;
        HT[hb + (size_t)dv * 256 + dk] = f2bf(st[nj][r]);
      }
    }

    f32x4 uacc[4] = {};
#pragma unroll
    for (int ks = 0; ks < 2; ++ks) {
      bf16x8 av = *(const bf16x8*)&Vs[cur][(w * 16 + fr) * 72 + ks * 32 + fq * 8];
#pragma unroll
      for (int nj = 0; nj < 4; ++nj) {
        bf16x8 bk = *(const bf16x8*)&Ks[cur][(nj * 16 + fr) * 72 + ks * 32 + fq * 8];
        uacc[nj] = __builtin_amdgcn_mfma_f32_16x16x32_bf16(av, bk, uacc[nj], 0, 0, 0);
      }
    }

    const float* ec = ebC + ((size_t)bh * NCHK + c) * 256 + dk0;
#pragma unroll
    for (int nj = 0; nj < 4; ++nj) {
      float e = ec[nj * 16 + fr];
      st[nj] = e * st[nj] + uacc[nj];
    }

    __syncthreads();
    if (c + 1 < NCHK) {
      WLDS(cur ^ 1, nvr, nkr);
      __syncthreads();
    }
  }
}

// ---------------------------------------------------------------------------
// attn_fused: per (bh,c), 4 waves. intra + inter + gated RMSNorm -> og bf16
// ---------------------------------------------------------------------------
__global__ __launch_bounds__(256) void attn_fused(
    const unsigned short* __restrict__ qt, const unsigned short* __restrict__ kt,
    const unsigned short* __restrict__ vT, const unsigned short* __restrict__ HT,
    const unsigned short* __restrict__ gp, const float* __restrict__ rw,
    unsigned short* __restrict__ og) {
  __shared__ unsigned short Qs[64 * 264];
  __shared__ unsigned short KVH[256 * 72];
  __shared__ unsigned short Sb[64 * 64];
  __shared__ float red[64][4];

  int bid = blockIdx.x;
  int c = bid & 31;
  int bh = bid >> 5;
  int b = bh >> 2, h = bh & 3;
  size_t rowbase = ((size_t)b * TT + c * 64) * 1024 + h * 256;
  size_t vtbase = (size_t)bh * 524288 + c * 64;
  size_t htbase = ((size_t)(bh * 32 + c)) * 65536;
  int tid = threadIdx.x;
  int lane = tid & 63;
  int w = tid >> 6;
  int fr = lane & 15, fq = lane >> 4;

#pragma unroll
  for (int i = 0; i < 8; ++i) {
    int gg = tid + i * 256;
    int row = gg >> 5, gc = gg & 31;
    *(bf16x8*)&Qs[row * 264 + gc * 8] =
        *(const bf16x8*)&qt[rowbase + (size_t)row * 1024 + gc * 8];
    *(bf16x8*)&KVH[row * 264 + gc * 8] =
        *(const bf16x8*)&kt[rowbase + (size_t)row * 1024 + gc * 8];
  }
  __syncthreads();

  {
    f32x4 accs[4] = {};
#pragma unroll
    for (int ks = 0; ks < 8; ++ks) {
      bf16x8 af = *(const bf16x8*)&Qs[(w * 16 + fr) * 264 + ks * 32 + fq * 8];
#pragma unroll
      for (int si = 0; si < 4; ++si) {
        bf16x8 bf_ = *(const bf16x8*)&KVH[(si * 16 + fr) * 264 + ks * 32 + fq * 8];
        accs[si] = __builtin_amdgcn_mfma_f32_16x16x32_bf16(af, bf_, accs[si], 0, 0, 0);
      }
    }
#pragma unroll
    for (int si = 0; si < 4; ++si) {
#pragma unroll
      for (int r = 0; r < 4; ++r) {
        int t = w * 16 + fq * 4 + r;
        int s = si * 16 + fr;
        float val = (s <= t) ? accs[si][r] : 0.0f;
        Sb[t * 64 + (((s >> 3) ^ (t & 7)) * 8) + (s & 7)] = f2bf(val);
      }
    }
  }
  __syncthreads();

#pragma unroll
  for (int i = 0; i < 8; ++i) {
    int gg = tid + i * 256;
    int dv = gg >> 3, gc = gg & 7;
    *(bf16x8*)&KVH[dv * 72 + gc * 8] =
        *(const bf16x8*)&vT[vtbase + (size_t)dv * 2048 + gc * 8];
  }
  __syncthreads();

  int dv0 = w * 64;
  f32x4 acc[4][4] = {};

#pragma unroll
  for (int ks = 0; ks < 2; ++ks) {
    bf16x8 af[4], bv[4];
#pragma unroll
    for (int ti = 0; ti < 4; ++ti) {
      int t = ti * 16 + fr;
      af[ti] = *(const bf16x8*)&Sb[t * 64 + (((ks * 4 + fq) ^ (t & 7)) * 8)];
    }
#pragma unroll
    for (int nj = 0; nj < 4; ++nj)
      bv[nj] = *(const bf16x8*)&KVH[(dv0 + nj * 16 + fr) * 72 + ks * 32 + fq * 8];
#pragma unroll
    for (int ti = 0; ti < 4; ++ti)
#pragma unroll
      for (int nj = 0; nj < 4; ++nj)
        acc[ti][nj] = __builtin_amdgcn_mfma_f32_16x16x32_bf16(af[ti], bv[nj],
                                                              acc[ti][nj], 0, 0, 0);
  }

  for (int k4 = 0; k4 < 4; ++k4) {
    __syncthreads();
#pragma unroll
    for (int i = 0; i < 8; ++i) {
      int gg = tid + i * 256;
      int dv = gg >> 3, gc = gg & 7;
      *(bf16x8*)&KVH[dv * 72 + gc * 8] =
          *(const bf16x8*)&HT[htbase + (size_t)dv * 256 + k4 * 64 + gc * 8];
    }
    __syncthreads();
#pragma unroll
    for (int ks = 0; ks < 2; ++ks) {
      bf16x8 af[4], bv[4];
#pragma unroll
      for (int ti = 0; ti < 4; ++ti)
        af[ti] = *(const bf16x8*)&Qs[(ti * 16 + fr) * 264 + k4 * 64 + ks * 32 + fq * 8];
#pragma unroll
      for (int nj = 0; nj < 4; ++nj)
        bv[nj] = *(const bf16x8*)&KVH[(dv0 + nj * 16 + fr) * 72 + ks * 32 + fq * 8];
#pragma unroll
      for (int ti = 0; ti < 4; ++ti)
#pragma unroll
        for (int nj = 0; nj < 4; ++nj)
          acc[ti][nj] = __builtin_amdgcn_mfma_f32_16x16x32_bf16(af[ti], bv[nj],
                                                                acc[ti][nj], 0, 0, 0);
    }
  }

  float rstd[4][4];
#pragma unroll
  for (int ti = 0; ti < 4; ++ti) {
#pragma unroll
    for (int r = 0; r < 4; ++r) {
      float s = 0.0f;
#pragma unroll
      for (int nj = 0; nj < 4; ++nj) {
        float v = acc[ti][nj][r];
        s += v * v;
      }
      s += __shfl_xor(s, 1);
      s += __shfl_xor(s, 2);
      s += __shfl_xor(s, 4);
      s += __shfl_xor(s, 8);
      rstd[ti][r] = s;
    }
  }
  if (fr == 0) {
#pragma unroll
    for (int ti = 0; ti < 4; ++ti)
#pragma unroll
      for (int r = 0; r < 4; ++r)
        red[ti * 16 + fq * 4 + r][w] = rstd[ti][r];
  }
  __syncthreads();
#pragma unroll
  for (int ti = 0; ti < 4; ++ti) {
#pragma unroll
    for (int r = 0; r < 4; ++r) {
      int t = ti * 16 + fq * 4 + r;
      float tot = red[t][0] + red[t][1] + red[t][2] + red[t][3];
      rstd[ti][r] = rsqrtf(tot * (1.0f / 256.0f) + 1e-5f);
    }
  }
#pragma unroll
  for (int ti = 0; ti < 4; ++ti) {
#pragma unroll
    for (int nj = 0; nj < 4; ++nj) {
      int dv = dv0 + nj * 16 + fr;
      float rwv = rw[dv];
#pragma unroll
      for (int r = 0; r < 4; ++r) {
        int t = ti * 16 + fq * 4 + r;
        float gv = bf2f(gp[rowbase + (size_t)t * 1024 + dv]);
        float sw = gv / (1.0f + expf(-gv));
        og[rowbase + (size_t)t * 1024 + dv] =
            f2bf(acc[ti][nj][r] * rstd[ti][r] * rwv * sw);
      }
    }
  }
}

// ---------------------------------------------------------------------------
extern "C" void kernel_launch(void* const* d_in, const int* in_sizes, int n_in,
                              void* d_out, int out_size, void* d_ws,
                              size_t ws_size, hipStream_t stream) {
  const float* x = (const float*)d_in[0];
  const float* ln1_w = (const float*)d_in[1];
  const float* ln1_b = (const float*)d_in[2];
  const float* Wq = (const float*)d_in[3];
  const float* Wk = (const float*)d_in[4];
  const float* Wv = (const float*)d_in[5];
  const float* Wg = (const float*)d_in[6];
  const float* Wgk1 = (const float*)d_in[7];
  const float* Wgk2 = (const float*)d_in[8];
  const float* bgk2 = (const float*)d_in[9];
  const float* rms_w = (const float*)d_in[10];
  const float* Wo = (const float*)d_in[11];
  const float* ln2_w = (const float*)d_in[12];
  const float* ln2_b = (const float*)d_in[13];
  const float* W1 = (const float*)d_in[14];
  const float* b1 = (const float*)d_in[15];
  const float* W2 = (const float*)d_in[16];
  const float* b2 = (const float*)d_in[17];
  float* out = (float*)d_out;

  const size_t S = SS;
  unsigned short* actb = (unsigned short*)d_ws;  // xn -> vT -> xn2
  unsigned short* qb = actb + S;
  unsigned short* kb = qb + S;
  unsigned short* vb = kb + S;
  unsigned short* gb = vb + S;
  unsigned short* gkb = gb + S;
  unsigned short* ogb = gkb + S;
  unsigned short* UH = ogb + 2 * S;              // HT (written by ustate)
  float* ebC = (float*)(UH + 4 * S);
  unsigned short* Wqkvgt = (unsigned short*)(ebC + 131072);
  unsigned short* Wot = Wqkvgt + 4194304;
  unsigned short* W1t = Wot + 1048576;
  unsigned short* W2t = W1t + 3145728;
  unsigned short* khatT = gkb;
  unsigned short* vT = actb;
  float* x1 = (float*)kb;
  unsigned short* hb = UH;

  dim3 blk(256);

  P5 p5;
  p5.w[0] = Wq;  p5.o[0] = Wqkvgt;
  p5.w[1] = Wk;  p5.o[1] = Wqkvgt + 1048576;
  p5.w[2] = Wv;  p5.o[2] = Wqkvgt + 2097152;
  p5.w[3] = Wg;  p5.o[3] = Wqkvgt + 3145728;
  p5.w[4] = Wo;  p5.o[4] = Wot;
  transpose5<<<dim3(32, 32, 5), blk, 0, stream>>>(p5);
  transpose_cast<<<dim3(96, 32), blk, 0, stream>>>(W1, W1t, 1024, 3072);
  transpose_cast<<<dim3(32, 96), blk, 0, stream>>>(W2, W2t, 3072, 1024);

  // 1. xn = LN(x)
  ln_kernel<<<RR, blk, 0, stream>>>(x, ln1_w, ln1_b, actb);

  // 2. merged q|k|v|g projection
  dim3 g4096(4096 / 128, RR / 128);
  gemm_bf16<5, 1><<<g4096, blk, 0, stream>>>(actb, Wqkvgt, nullptr, nullptr, qb,
                                             RR, 4096, 1024);

  // 3. gk -> gkb
  gk_kernel<<<RR / 16, blk, 0, stream>>>(actb, Wgk1, Wgk2, bgk2, gkb);

  // 4. gate transforms (in-place q,k), ebC
  gate_chunk<<<BB * HH * NCHK, blk, 0, stream>>>(gkb, qb, kb, ebC);

  // 5. both transposes in one launch: khatT over gkb; vT over actb
  trans2<<<2 * 16 * 32 * 4, blk, 0, stream>>>(kb, vb, ebC, khatT, vT);

  // 6. fused U + scan -> HT (UH region)
  ustate_kernel<<<16 * 16, blk, 0, stream>>>(khatT, vT, ebC, UH);

  // 7. fused intra + inter + gated rmsnorm -> ogb
  attn_fused<<<16 * NCHK, blk, 0, stream>>>(qb, kb, vT, UH, gb, rms_w, ogb);

  // 8. x1 = x + og @ Wo
  dim3 g1024(1024 / 128, RR / 128);
  gemm_bf16<3, 0><<<g1024, blk, 0, stream>>>(ogb, Wot, nullptr, x, x1, RR, 1024, 1024);

  // 9. xn2 = LN(x1) -> actb
  ln_kernel<<<RR, blk, 0, stream>>>(x1, ln2_w, ln2_b, actb);

  // 10. h = (leaky_relu(xn2@W1+b1))^2 -> hb
  dim3 g3072(3072 / 128, RR / 128);
  gemm_bf16<2, 1><<<g3072, blk, 0, stream>>>(actb, W1t, b1, nullptr, hb, RR, 3072, 1024);

  // 11. out = x1 + h @ W2 + b2
  gemm_bf16<4, 0><<<g1024, blk, 0, stream>>>(hb, W2t, b2, x1, out, RR, 1024, 3072);
}

// Round 15
// 396.611 us; speedup vs baseline: 1.1158x; 1.0390x over previous
//
#include <hip/hip_runtime.h>
#include <math.h>

// Problem constants
#define BB 4
#define TT 2048
#define DD 1024
#define HH 4
#define DK 256
#define DV 256
#define RR 8192
#define CHK 64
#define NCHK 32
#define SS ((size_t)RR * DD)

typedef __bf16 bf16x8 __attribute__((ext_vector_type(8)));
typedef float f32x4 __attribute__((ext_vector_type(4)));

static __device__ inline unsigned short f2bf(float f) {
  unsigned int u = __float_as_uint(f);
  unsigned int r = (u + 0x7fffu + ((u >> 16) & 1u)) >> 16;
  return (unsigned short)r;
}
static __device__ inline float bf2f(unsigned short h) {
  return __uint_as_float(((unsigned int)h) << 16);
}

// async global->LDS, 16B per lane; dest = wave-uniform base + lane*16
static __device__ __forceinline__ void gload16(const unsigned short* g,
                                               unsigned short* l) {
  __builtin_amdgcn_global_load_lds(
      (const __attribute__((address_space(1))) void*)g,
      (__attribute__((address_space(3))) void*)l, 16, 0, 0);
}

// ---------------------------------------------------------------------------
// LayerNorm: one block per row of D=1024. INBF: f32 vs bf16 input. bf16 out.
// ---------------------------------------------------------------------------
template <int INBF>
__global__ __launch_bounds__(256) void ln_kernel(const void* __restrict__ xv,
                                                 const float* __restrict__ w,
                                                 const float* __restrict__ b,
                                                 unsigned short* __restrict__ yb) {
  int row = blockIdx.x;
  int tid = threadIdx.x;
  unsigned short* ybr = yb + (size_t)row * DD;

  float e0, e1, e2, e3;
  if (INBF) {
    const unsigned short* xr = (const unsigned short*)xv + (size_t)row * DD;
    ushort4 u = ((const ushort4*)xr)[tid];
    e0 = bf2f(u.x); e1 = bf2f(u.y); e2 = bf2f(u.z); e3 = bf2f(u.w);
  } else {
    const float* xr = (const float*)xv + (size_t)row * DD;
    float4 v = ((const float4*)xr)[tid];
    e0 = v.x; e1 = v.y; e2 = v.z; e3 = v.w;
  }
  float s = e0 + e1 + e2 + e3;
  float ss = e0 * e0 + e1 * e1 + e2 * e2 + e3 * e3;
#pragma unroll
  for (int o = 32; o > 0; o >>= 1) {
    s += __shfl_down(s, o);
    ss += __shfl_down(ss, o);
  }
  __shared__ float ls[4], lss[4];
  int wid = tid >> 6;
  if ((tid & 63) == 0) { ls[wid] = s; lss[wid] = ss; }
  __syncthreads();
  float sum = ls[0] + ls[1] + ls[2] + ls[3];
  float sumsq = lss[0] + lss[1] + lss[2] + lss[3];
  float mu = sum * (1.0f / DD);
  float var = sumsq * (1.0f / DD) - mu * mu;
  float rs = rsqrtf(var + 1e-5f);

  float4 wv = ((const float4*)w)[tid];
  float4 bv = ((const float4*)b)[tid];
  ushort4 ob;
  ob.x = f2bf((e0 - mu) * rs * wv.x + bv.x);
  ob.y = f2bf((e1 - mu) * rs * wv.y + bv.y);
  ob.z = f2bf((e2 - mu) * rs * wv.z + bv.z);
  ob.w = f2bf((e3 - mu) * rs * wv.w + bv.w);
  ((ushort4*)ybr)[tid] = ob;
}

// ---------------------------------------------------------------------------
// Weight transpose + cast: W [K,N] f32 -> Wt [N,K] bf16
// ---------------------------------------------------------------------------
__global__ __launch_bounds__(256) void transpose_cast(const float* __restrict__ W,
                                                      unsigned short* __restrict__ Wt,
                                                      int K, int N) {
  __shared__ float t[32][33];
  int k0 = blockIdx.y * 32, n0 = blockIdx.x * 32;
  int tid = threadIdx.x;
  int tx = tid & 31, ty = tid >> 5;  // ty 0..7
#pragma unroll
  for (int i = 0; i < 4; ++i)
    t[ty + i * 8][tx] = W[(size_t)(k0 + ty + i * 8) * N + n0 + tx];
  __syncthreads();
#pragma unroll
  for (int i = 0; i < 4; ++i)
    Wt[(size_t)(n0 + ty + i * 8) * K + k0 + tx] = f2bf(t[tx][ty + i * 8]);
}

// batched 1024x1024 transpose (5 matrices in one launch)
struct P5 {
  const float* w[5];
  unsigned short* o[5];
};
__global__ __launch_bounds__(256) void transpose5(P5 p) {
  __shared__ float t[32][33];
  int z = blockIdx.z;
  const float* W = p.w[z];
  unsigned short* Wt = p.o[z];
  int k0 = blockIdx.y * 32, n0 = blockIdx.x * 32;
  int tid = threadIdx.x;
  int tx = tid & 31, ty = tid >> 5;
#pragma unroll
  for (int i = 0; i < 4; ++i)
    t[ty + i * 8][tx] = W[(size_t)(k0 + ty + i * 8) * 1024 + n0 + tx];
  __syncthreads();
#pragma unroll
  for (int i = 0; i < 4; ++i)
    Wt[(size_t)(n0 + ty + i * 8) * 1024 + k0 + tx] = f2bf(t[tx][ty + i * 8]);
}

// ---------------------------------------------------------------------------
// bf16 MFMA GEMM: C[M,N] = A[M,K] @ Bt[N,K]^T  (+epilogue)
// 128x128 tile, BK=64, double-buffered global_load_lds staging, XOR-swizzled
// LDS (granule ^= row&7; 0 conflicts measured), XCD block swizzle.
// EPI: 0 none, 2 +bias,(leaky)^2, 3 +f32res, 4 +bias+f32res,
//      5 proj fan-out, 6 +bias+bf16res (f32 out).
// ---------------------------------------------------------------------------
template <int EPI, int OUTBF>
__global__ __launch_bounds__(256) void gemm_bf16(
    const unsigned short* __restrict__ A,   // [M,K] bf16
    const unsigned short* __restrict__ Bt,  // [N,K] bf16
    const float* __restrict__ bias, const void* __restrict__ Res,
    void* __restrict__ Cv, int M, int N, int K) {
  __shared__ unsigned short As[2][128 * 64];  // [buf][row][64 bf16]
  __shared__ unsigned short Bs[2][128 * 64];
  int tid = threadIdx.x;
  // XCD-aware swizzle (nwg % 8 == 0)
  int nwg = gridDim.x * gridDim.y;
  int wg = blockIdx.y * gridDim.x + blockIdx.x;
  int cpx = nwg >> 3;
  wg = (wg & 7) * cpx + (wg >> 3);
  int m0 = (wg / gridDim.x) * 128, n0 = (wg % gridDim.x) * 128;
  int lane = tid & 63;
  int w64 = tid & 192;  // wave * 64
  int wid = tid >> 6;
  int wm = (wid >> 1) * 64, wn = (wid & 1) * 64;
  int fr = lane & 15, fq = lane >> 4;

  f32x4 acc[4][4] = {};

  auto STAGE = [&](int buf, int k0) {
#pragma unroll
    for (int j = 0; j < 4; ++j) {
      int gl = j * 256 + tid;           // granule 0..1023
      int row = gl >> 3;
      int gs = (gl & 7) ^ (row & 7);    // inverse-swizzled source granule
      gload16(&A[(size_t)(m0 + row) * K + k0 + gs * 8],
              &As[buf][(size_t)(j * 256 + w64) * 8]);
      gload16(&Bt[(size_t)(n0 + row) * K + k0 + gs * 8],
              &Bs[buf][(size_t)(j * 256 + w64) * 8]);
    }
  };

  STAGE(0, 0);
  asm volatile("s_waitcnt vmcnt(0)");
  __syncthreads();

  int cur = 0;
  for (int k0 = 0; k0 < K; k0 += 64) {
    if (k0 + 64 < K) STAGE(cur ^ 1, k0 + 64);  // prefetch next tile

#pragma unroll
    for (int ph = 0; ph < 2; ++ph) {
      bf16x8 af[4], bv[4];
#pragma unroll
      for (int i = 0; i < 4; ++i) {
        int ra = wm + i * 16 + fr;
        af[i] = *(const bf16x8*)&As[cur][ra * 64 + (((ph * 4 + fq) ^ (ra & 7)) * 8)];
        int rb = wn + i * 16 + fr;
        bv[i] = *(const bf16x8*)&Bs[cur][rb * 64 + (((ph * 4 + fq) ^ (rb & 7)) * 8)];
      }
#pragma unroll
      for (int i = 0; i < 4; ++i)
#pragma unroll
        for (int jj = 0; jj < 4; ++jj)
          acc[i][jj] = __builtin_amdgcn_mfma_f32_16x16x32_bf16(af[i], bv[jj],
                                                               acc[i][jj], 0, 0, 0);
    }
    __syncthreads();  // drains vmcnt -> prefetched tile visible; buffers safe
    cur ^= 1;
  }

  // epilogue: C/D layout col=lane&15, row=(lane>>4)*4+r
  int col = lane & 15;
  int rbase = (lane >> 4) * 4;
#pragma unroll
  for (int i = 0; i < 4; ++i) {
#pragma unroll
    for (int j = 0; j < 4; ++j) {
      int n = n0 + wn + j * 16 + col;
      float bvv = (EPI == 2 || EPI == 4 || EPI == 6) ? bias[n] : 0.0f;
#pragma unroll
      for (int r = 0; r < 4; ++r) {
        int m = m0 + wm + i * 16 + rbase + r;
        float vv = acc[i][j][r] + bvv;
        if (EPI == 2) {
          float t = vv > 0.0f ? vv : 0.01f * vv;
          vv = t * t;
        }
        if (EPI == 3 || EPI == 4)
          vv += ((const float*)Res)[(size_t)m * N + n];
        if (EPI == 6)
          vv += bf2f(((const unsigned short*)Res)[(size_t)m * N + n]);
        if (EPI == 5) {
          ((unsigned short*)Cv)[(size_t)(n >> 10) * SS + (size_t)m * 1024 +
                                (n & 1023)] = f2bf(vv);
        } else if (OUTBF) {
          ((unsigned short*)Cv)[(size_t)m * N + n] = f2bf(vv);
        } else {
          ((float*)Cv)[(size_t)m * N + n] = vv;
        }
      }
    }
  }
}

// ---------------------------------------------------------------------------
// Low-rank forget gate -> LOG gate gk = log_sigmoid(z)/16
// 16 rows per block; xn + Wgk1(bf16) staged in LDS; Wgk2 amortized 16x via L2.
// ---------------------------------------------------------------------------
__global__ __launch_bounds__(256) void gk_kernel(const unsigned short* __restrict__ xn,
                                                 const float* __restrict__ Wgk1,
                                                 const float* __restrict__ Wgk2,
                                                 const float* __restrict__ bgk2,
                                                 unsigned short* __restrict__ gk) {
  __shared__ unsigned short Xs[16 * 1024];  // 32KB: xn rows, later out tile
  __shared__ unsigned short W1s[1024 * 16]; // 32KB: Wgk1 bf16
  __shared__ float Ts[16][16];
  int r0 = blockIdx.x * 16;
  int tid = threadIdx.x;

#pragma unroll
  for (int i = 0; i < 16; ++i) {
    int idx = tid + i * 256;
    ((ushort4*)Xs)[idx] = ((const ushort4*)(xn + (size_t)r0 * 1024))[idx];
  }
#pragma unroll
  for (int i = 0; i < 16; ++i) {
    int idx = tid + i * 256;
    float4 w = ((const float4*)Wgk1)[idx];
    ushort4 hh;
    hh.x = f2bf(w.x); hh.y = f2bf(w.y); hh.z = f2bf(w.z); hh.w = f2bf(w.w);
    ((ushort4*)W1s)[idx] = hh;
  }
  __syncthreads();

  {
    int r = tid >> 4, part = tid & 15;
    float t16[16];
#pragma unroll
    for (int j = 0; j < 16; ++j) t16[j] = 0.0f;
    for (int dd = 0; dd < 64; ++dd) {
      int d = dd * 16 + part;
      float xv = bf2f(Xs[r * 1024 + d]);
      const ushort4* wr = (const ushort4*)&W1s[d * 16];
#pragma unroll
      for (int q4 = 0; q4 < 4; ++q4) {
        ushort4 w = wr[q4];
        t16[q4 * 4 + 0] += xv * bf2f(w.x);
        t16[q4 * 4 + 1] += xv * bf2f(w.y);
        t16[q4 * 4 + 2] += xv * bf2f(w.z);
        t16[q4 * 4 + 3] += xv * bf2f(w.w);
      }
    }
#pragma unroll
    for (int j = 0; j < 16; ++j) {
      float s = t16[j];
      s += __shfl_xor(s, 1);
      s += __shfl_xor(s, 2);
      s += __shfl_xor(s, 4);
      s += __shfl_xor(s, 8);
      t16[j] = s;
    }
    if (part == 0) {
#pragma unroll
      for (int j = 0; j < 16; ++j) Ts[r][j] = t16[j];
    }
  }
  __syncthreads();

  {
    float w2[16][4];
#pragma unroll
    for (int j = 0; j < 16; ++j) {
      float4 wv = *(const float4*)&Wgk2[(size_t)j * 1024 + tid * 4];
      w2[j][0] = wv.x; w2[j][1] = wv.y; w2[j][2] = wv.z; w2[j][3] = wv.w;
    }
    float4 bv = *(const float4*)&bgk2[tid * 4];
    float bb[4] = {bv.x, bv.y, bv.z, bv.w};
#pragma unroll
    for (int r = 0; r < 16; ++r) {
      ushort4 outv;
      unsigned short* op = (unsigned short*)&outv;
#pragma unroll
      for (int jj = 0; jj < 4; ++jj) {
        float z = bb[jj];
#pragma unroll
        for (int j = 0; j < 16; ++j) z += Ts[r][j] * w2[j][jj];
        float lsg = fminf(z, 0.0f) - log1pf(expf(-fabsf(z)));
        op[jj] = f2bf(lsg * (1.0f / 16.0f));
      }
      *(ushort4*)&Xs[r * 1024 + tid * 4] = outv;
    }
  }
  __syncthreads();
#pragma unroll
  for (int i = 0; i < 16; ++i) {
    int idx = tid + i * 256;
    ((ushort4*)(gk + (size_t)r0 * 1024))[idx] = ((const ushort4*)Xs)[idx];
  }
}

// ---------------------------------------------------------------------------
// gate_trans: fuses gate_chunk + trans2. grid = (bh,ct,dt) = 2048 blocks,
// one 64t x 64d slice. Phases: stage gk -> 4-group cumsum -> q~ (row-major),
// k~ (row-major + transposed khatT with ebv fold), v -> vT. ebC written.
// ---------------------------------------------------------------------------
__global__ __launch_bounds__(256) void gate_trans(
    const unsigned short* __restrict__ gk, unsigned short* __restrict__ q,
    unsigned short* __restrict__ k, const unsigned short* __restrict__ v,
    float* __restrict__ ebC, unsigned short* __restrict__ khatT,
    unsigned short* __restrict__ vT) {
  __shared__ float Gs[64][65];      // cum(t, col)
  __shared__ unsigned short T[64][68];
  __shared__ float P[4][64];
  __shared__ float E[64];
  int bid = blockIdx.x;
  int dt = bid & 3;
  int ct = (bid >> 2) & 31;
  int bh = bid >> 7;
  int b = bh >> 2, h = bh & 3;
  int tid = threadIdx.x;
  int r = tid >> 4;            // 0..15
  int c4 = (tid & 15) * 4;
  size_t srcbase = ((size_t)b * TT + ct * 64) * 1024 + h * 256 + dt * 64;
  size_t outbase = (size_t)bh * 524288 + (size_t)(dt * 64) * 2048 + ct * 64;

  // stage gk slice -> Gs (as f32)
#pragma unroll
  for (int i = 0; i < 4; ++i) {
    ushort4 g4 = *(const ushort4*)&gk[srcbase + (size_t)(r + i * 16) * 1024 + c4];
    Gs[r + i * 16][c4 + 0] = bf2f(g4.x);
    Gs[r + i * 16][c4 + 1] = bf2f(g4.y);
    Gs[r + i * 16][c4 + 2] = bf2f(g4.z);
    Gs[r + i * 16][c4 + 3] = bf2f(g4.w);
  }
  __syncthreads();

  // cumsum along t per column: thread (col=tid&63, grp=tid>>6) owns 16 t's
  {
    int col = tid & 63, grp = tid >> 6;
    float s = 0.0f;
#pragma unroll
    for (int t = 0; t < 16; ++t) s += Gs[grp * 16 + t][col];
    P[grp][col] = s;
  }
  __syncthreads();
  {
    int col = tid & 63, grp = tid >> 6;
    float base = 0.0f;
#pragma unroll
    for (int j = 0; j < 4; ++j)
      if (j < grp) base += P[j][col];
    float cum = base;
#pragma unroll
    for (int t = 0; t < 16; ++t) {
      cum += Gs[grp * 16 + t][col];
      Gs[grp * 16 + t][col] = cum;
    }
    if (grp == 3) {
      float ebv = expf(cum);
      E[col] = ebv;
      ebC[((size_t)bh * NCHK + ct) * 256 + dt * 64 + col] = ebv;
    }
  }
  __syncthreads();

  const float scale = 0.0625f;
  // q~ = q * exp(cum) * scale (row-major, in place)
#pragma unroll
  for (int i = 0; i < 4; ++i) {
    int t = r + i * 16;
    size_t a = srcbase + (size_t)t * 1024 + c4;
    ushort4 q4 = *(const ushort4*)&q[a];
    ushort4 o;
    o.x = f2bf(bf2f(q4.x) * expf(Gs[t][c4 + 0]) * scale);
    o.y = f2bf(bf2f(q4.y) * expf(Gs[t][c4 + 1]) * scale);
    o.z = f2bf(bf2f(q4.z) * expf(Gs[t][c4 + 2]) * scale);
    o.w = f2bf(bf2f(q4.w) * expf(Gs[t][c4 + 3]) * scale);
    *(ushort4*)&q[a] = o;
  }

  // k~ = k * exp(-cum): write row-major (in place) + stage to T
#pragma unroll
  for (int i = 0; i < 4; ++i) {
    int t = r + i * 16;
    size_t a = srcbase + (size_t)t * 1024 + c4;
    ushort4 k4 = *(const ushort4*)&k[a];
    ushort4 o;
    o.x = f2bf(bf2f(k4.x) * expf(-Gs[t][c4 + 0]));
    o.y = f2bf(bf2f(k4.y) * expf(-Gs[t][c4 + 1]));
    o.z = f2bf(bf2f(k4.z) * expf(-Gs[t][c4 + 2]));
    o.w = f2bf(bf2f(k4.w) * expf(-Gs[t][c4 + 3]));
    *(ushort4*)&k[a] = o;
    *(ushort4*)&T[t][c4] = o;
  }
  __syncthreads();
  // khatT[dk][t] = k~[t][dk] * ebv[dk]
#pragma unroll
  for (int i = 0; i < 4; ++i) {
    int dkl = r + i * 16;
    float e = E[dkl];
    ushort4 o;
    o.x = f2bf(bf2f(T[c4 + 0][dkl]) * e);
    o.y = f2bf(bf2f(T[c4 + 1][dkl]) * e);
    o.z = f2bf(bf2f(T[c4 + 2][dkl]) * e);
    o.w = f2bf(bf2f(T[c4 + 3][dkl]) * e);
    *(ushort4*)&khatT[outbase + (size_t)dkl * 2048 + c4] = o;
  }
  __syncthreads();
  // v -> vT
#pragma unroll
  for (int i = 0; i < 4; ++i)
    *(ushort4*)&T[r + i * 16][c4] =
        *(const ushort4*)&v[srcbase + (size_t)(r + i * 16) * 1024 + c4];
  __syncthreads();
#pragma unroll
  for (int i = 0; i < 4; ++i) {
    int dvl = r + i * 16;
    ushort4 o;
    o.x = T[c4 + 0][dvl];
    o.y = T[c4 + 1][dvl];
    o.z = T[c4 + 2][dvl];
    o.w = T[c4 + 3][dvl];
    *(ushort4*)&vT[outbase + (size_t)dvl * 2048 + c4] = o;
  }
}

// ---------------------------------------------------------------------------
// ustate_kernel: fused U+scan. grid = 16bh x 16 tiles (4dv x 4dk), 256 thr.
// ---------------------------------------------------------------------------
__global__ __launch_bounds__(256) void ustate_kernel(
    const unsigned short* __restrict__ khatT, const unsigned short* __restrict__ vT,
    const float* __restrict__ ebC, unsigned short* __restrict__ HT) {
  __shared__ unsigned short Vs[2][64 * 72];
  __shared__ unsigned short Ks[2][64 * 72];
  int bid = blockIdx.x;
  int tile = bid & 15;
  int bh = bid >> 4;
  int dv0 = (tile >> 2) * 64, dk0 = (tile & 3) * 64;
  const unsigned short* Vb = vT + (size_t)bh * 524288 + (size_t)dv0 * 2048;
  const unsigned short* Kb = khatT + (size_t)bh * 524288 + (size_t)dk0 * 2048;
  int tid = threadIdx.x;
  int lane = tid & 63;
  int w = tid >> 6;
  int fr = lane & 15, fq = lane >> 4;

  bf16x8 vr[2], kr[2], nvr[2], nkr[2];
  auto LOADR = [&](int c, bf16x8 vv[2], bf16x8 kk[2]) {
#pragma unroll
    for (int j = 0; j < 2; ++j) {
      int g = j * 256 + tid;
      int row = g >> 3, gc = g & 7;
      vv[j] = *(const bf16x8*)&Vb[(size_t)row * 2048 + c * 64 + gc * 8];
      kk[j] = *(const bf16x8*)&Kb[(size_t)row * 2048 + c * 64 + gc * 8];
    }
  };
  auto WLDS = [&](int buf, bf16x8 vv[2], bf16x8 kk[2]) {
#pragma unroll
    for (int j = 0; j < 2; ++j) {
      int g = j * 256 + tid;
      int row = g >> 3, gc = g & 7;
      *(bf16x8*)&Vs[buf][row * 72 + gc * 8] = vv[j];
      *(bf16x8*)&Ks[buf][row * 72 + gc * 8] = kk[j];
    }
  };

  f32x4 st[4] = {};

  LOADR(0, vr, kr);
  WLDS(0, vr, kr);
  __syncthreads();

  for (int c = 0; c < NCHK; ++c) {
    int cur = c & 1;
    if (c + 1 < NCHK) LOADR(c + 1, nvr, nkr);

    size_t hb = ((size_t)(bh * NCHK + c)) * 65536;
#pragma unroll
    for (int nj = 0; nj < 4; ++nj) {
#pragma unroll
      for (int r = 0; r < 4; ++r) {
        int dv = dv0 + w * 16 + fq * 4 + r;
        int dk = dk0 + nj * 16 + fr;
        HT[hb + (size_t)dv * 256 + dk] = f2bf(st[nj][r]);
      }
    }

    f32x4 uacc[4] = {};
#pragma unroll
    for (int ks = 0; ks < 2; ++ks) {
      bf16x8 av = *(const bf16x8*)&Vs[cur][(w * 16 + fr) * 72 + ks * 32 + fq * 8];
#pragma unroll
      for (int nj = 0; nj < 4; ++nj) {
        bf16x8 bk = *(const bf16x8*)&Ks[cur][(nj * 16 + fr) * 72 + ks * 32 + fq * 8];
        uacc[nj] = __builtin_amdgcn_mfma_f32_16x16x32_bf16(av, bk, uacc[nj], 0, 0, 0);
      }
    }

    const float* ec = ebC + ((size_t)bh * NCHK + c) * 256 + dk0;
#pragma unroll
    for (int nj = 0; nj < 4; ++nj) {
      float e = ec[nj * 16 + fr];
      st[nj] = e * st[nj] + uacc[nj];
    }

    __syncthreads();
    if (c + 1 < NCHK) {
      WLDS(cur ^ 1, nvr, nkr);
      __syncthreads();
    }
  }
}

// ---------------------------------------------------------------------------
// attn_fused: per (bh,c), 4 waves. intra + inter + gated RMSNorm -> og bf16
// ---------------------------------------------------------------------------
__global__ __launch_bounds__(256) void attn_fused(
    const unsigned short* __restrict__ qt, const unsigned short* __restrict__ kt,
    const unsigned short* __restrict__ vT, const unsigned short* __restrict__ HT,
    const unsigned short* __restrict__ gp, const float* __restrict__ rw,
    unsigned short* __restrict__ og) {
  __shared__ unsigned short Qs[64 * 264];
  __shared__ unsigned short KVH[256 * 72];
  __shared__ unsigned short Sb[64 * 64];
  __shared__ float red[64][4];

  int bid = blockIdx.x;
  int c = bid & 31;
  int bh = bid >> 5;
  int b = bh >> 2, h = bh & 3;
  size_t rowbase = ((size_t)b * TT + c * 64) * 1024 + h * 256;
  size_t vtbase = (size_t)bh * 524288 + c * 64;
  size_t htbase = ((size_t)(bh * 32 + c)) * 65536;
  int tid = threadIdx.x;
  int lane = tid & 63;
  int w = tid >> 6;
  int fr = lane & 15, fq = lane >> 4;

#pragma unroll
  for (int i = 0; i < 8; ++i) {
    int gg = tid + i * 256;
    int row = gg >> 5, gc = gg & 31;
    *(bf16x8*)&Qs[row * 264 + gc * 8] =
        *(const bf16x8*)&qt[rowbase + (size_t)row * 1024 + gc * 8];
    *(bf16x8*)&KVH[row * 264 + gc * 8] =
        *(const bf16x8*)&kt[rowbase + (size_t)row * 1024 + gc * 8];
  }
  __syncthreads();

  {
    f32x4 accs[4] = {};
#pragma unroll
    for (int ks = 0; ks < 8; ++ks) {
      bf16x8 af = *(const bf16x8*)&Qs[(w * 16 + fr) * 264 + ks * 32 + fq * 8];
#pragma unroll
      for (int si = 0; si < 4; ++si) {
        bf16x8 bf_ = *(const bf16x8*)&KVH[(si * 16 + fr) * 264 + ks * 32 + fq * 8];
        accs[si] = __builtin_amdgcn_mfma_f32_16x16x32_bf16(af, bf_, accs[si], 0, 0, 0);
      }
    }
#pragma unroll
    for (int si = 0; si < 4; ++si) {
#pragma unroll
      for (int r = 0; r < 4; ++r) {
        int t = w * 16 + fq * 4 + r;
        int s = si * 16 + fr;
        float val = (s <= t) ? accs[si][r] : 0.0f;
        Sb[t * 64 + (((s >> 3) ^ (t & 7)) * 8) + (s & 7)] = f2bf(val);
      }
    }
  }
  __syncthreads();

#pragma unroll
  for (int i = 0; i < 8; ++i) {
    int gg = tid + i * 256;
    int dv = gg >> 3, gc = gg & 7;
    *(bf16x8*)&KVH[dv * 72 + gc * 8] =
        *(const bf16x8*)&vT[vtbase + (size_t)dv * 2048 + gc * 8];
  }
  __syncthreads();

  int dv0 = w * 64;
  f32x4 acc[4][4] = {};

#pragma unroll
  for (int ks = 0; ks < 2; ++ks) {
    bf16x8 af[4], bv[4];
#pragma unroll
    for (int ti = 0; ti < 4; ++ti) {
      int t = ti * 16 + fr;
      af[ti] = *(const bf16x8*)&Sb[t * 64 + (((ks * 4 + fq) ^ (t & 7)) * 8)];
    }
#pragma unroll
    for (int nj = 0; nj < 4; ++nj)
      bv[nj] = *(const bf16x8*)&KVH[(dv0 + nj * 16 + fr) * 72 + ks * 32 + fq * 8];
#pragma unroll
    for (int ti = 0; ti < 4; ++ti)
#pragma unroll
      for (int nj = 0; nj < 4; ++nj)
        acc[ti][nj] = __builtin_amdgcn_mfma_f32_16x16x32_bf16(af[ti], bv[nj],
                                                              acc[ti][nj], 0, 0, 0);
  }

  for (int k4 = 0; k4 < 4; ++k4) {
    __syncthreads();
#pragma unroll
    for (int i = 0; i < 8; ++i) {
      int gg = tid + i * 256;
      int dv = gg >> 3, gc = gg & 7;
      *(bf16x8*)&KVH[dv * 72 + gc * 8] =
          *(const bf16x8*)&HT[htbase + (size_t)dv * 256 + k4 * 64 + gc * 8];
    }
    __syncthreads();
#pragma unroll
    for (int ks = 0; ks < 2; ++ks) {
      bf16x8 af[4], bv[4];
#pragma unroll
      for (int ti = 0; ti < 4; ++ti)
        af[ti] = *(const bf16x8*)&Qs[(ti * 16 + fr) * 264 + k4 * 64 + ks * 32 + fq * 8];
#pragma unroll
      for (int nj = 0; nj < 4; ++nj)
        bv[nj] = *(const bf16x8*)&KVH[(dv0 + nj * 16 + fr) * 72 + ks * 32 + fq * 8];
#pragma unroll
      for (int ti = 0; ti < 4; ++ti)
#pragma unroll
        for (int nj = 0; nj < 4; ++nj)
          acc[ti][nj] = __builtin_amdgcn_mfma_f32_16x16x32_bf16(af[ti], bv[nj],
                                                                acc[ti][nj], 0, 0, 0);
    }
  }

  float rstd[4][4];
#pragma unroll
  for (int ti = 0; ti < 4; ++ti) {
#pragma unroll
    for (int r = 0; r < 4; ++r) {
      float s = 0.0f;
#pragma unroll
      for (int nj = 0; nj < 4; ++nj) {
        float v = acc[ti][nj][r];
        s += v * v;
      }
      s += __shfl_xor(s, 1);
      s += __shfl_xor(s, 2);
      s += __shfl_xor(s, 4);
      s += __shfl_xor(s, 8);
      rstd[ti][r] = s;
    }
  }
  if (fr == 0) {
#pragma unroll
    for (int ti = 0; ti < 4; ++ti)
#pragma unroll
      for (int r = 0; r < 4; ++r)
        red[ti * 16 + fq * 4 + r][w] = rstd[ti][r];
  }
  __syncthreads();
#pragma unroll
  for (int ti = 0; ti < 4; ++ti) {
#pragma unroll
    for (int r = 0; r < 4; ++r) {
      int t = ti * 16 + fq * 4 + r;
      float tot = red[t][0] + red[t][1] + red[t][2] + red[t][3];
      rstd[ti][r] = rsqrtf(tot * (1.0f / 256.0f) + 1e-5f);
    }
  }
#pragma unroll
  for (int ti = 0; ti < 4; ++ti) {
#pragma unroll
    for (int nj = 0; nj < 4; ++nj) {
      int dv = dv0 + nj * 16 + fr;
      float rwv = rw[dv];
#pragma unroll
      for (int r = 0; r < 4; ++r) {
        int t = ti * 16 + fq * 4 + r;
        float gv = bf2f(gp[rowbase + (size_t)t * 1024 + dv]);
        float sw = gv / (1.0f + expf(-gv));
        og[rowbase + (size_t)t * 1024 + dv] =
            f2bf(acc[ti][nj][r] * rstd[ti][r] * rwv * sw);
      }
    }
  }
}

// ---------------------------------------------------------------------------
extern "C" void kernel_launch(void* const* d_in, const int* in_sizes, int n_in,
                              void* d_out, int out_size, void* d_ws,
                              size_t ws_size, hipStream_t stream) {
  const float* x = (const float*)d_in[0];
  const float* ln1_w = (const float*)d_in[1];
  const float* ln1_b = (const float*)d_in[2];
  const float* Wq = (const float*)d_in[3];
  const float* Wk = (const float*)d_in[4];
  const float* Wv = (const float*)d_in[5];
  const float* Wg = (const float*)d_in[6];
  const float* Wgk1 = (const float*)d_in[7];
  const float* Wgk2 = (const float*)d_in[8];
  const float* bgk2 = (const float*)d_in[9];
  const float* rms_w = (const float*)d_in[10];
  const float* Wo = (const float*)d_in[11];
  const float* ln2_w = (const float*)d_in[12];
  const float* ln2_b = (const float*)d_in[13];
  const float* W1 = (const float*)d_in[14];
  const float* b1 = (const float*)d_in[15];
  const float* W2 = (const float*)d_in[16];
  const float* b2 = (const float*)d_in[17];
  float* out = (float*)d_out;

  const size_t S = SS;
  unsigned short* actb = (unsigned short*)d_ws;  // xn -> vT -> xn2
  unsigned short* qb = actb + S;
  unsigned short* kb = qb + S;                   // k~ ; x1 bf16 (late)
  unsigned short* vb = kb + S;
  unsigned short* gb = vb + S;
  unsigned short* gkb = gb + S;                  // gk
  unsigned short* ogb = gkb + S;                 // og (S) + khatT (S spare)
  unsigned short* UH = ogb + 2 * S;              // HT (written by ustate)
  float* ebC = (float*)(UH + 4 * S);
  unsigned short* Wqkvgt = (unsigned short*)(ebC + 131072);
  unsigned short* Wot = Wqkvgt + 4194304;
  unsigned short* W1t = Wot + 1048576;
  unsigned short* W2t = W1t + 3145728;
  unsigned short* khatT = ogb + S;   // spare half of ogb region
  unsigned short* vT = actb;         // xn dead after gk
  unsigned short* x1 = kb;           // bf16 x1 over kb (k~ dead after attn)
  unsigned short* hb = UH;           // MLP hidden 3S bf16 (HT dead after attn)

  dim3 blk(256);

  P5 p5;
  p5.w[0] = Wq;  p5.o[0] = Wqkvgt;
  p5.w[1] = Wk;  p5.o[1] = Wqkvgt + 1048576;
  p5.w[2] = Wv;  p5.o[2] = Wqkvgt + 2097152;
  p5.w[3] = Wg;  p5.o[3] = Wqkvgt + 3145728;
  p5.w[4] = Wo;  p5.o[4] = Wot;
  transpose5<<<dim3(32, 32, 5), blk, 0, stream>>>(p5);
  transpose_cast<<<dim3(96, 32), blk, 0, stream>>>(W1, W1t, 1024, 3072);
  transpose_cast<<<dim3(32, 96), blk, 0, stream>>>(W2, W2t, 3072, 1024);

  // 1. xn = LN(x) (f32 in)
  ln_kernel<0><<<RR, blk, 0, stream>>>(x, ln1_w, ln1_b, actb);

  // 2. merged q|k|v|g projection
  dim3 g4096(4096 / 128, RR / 128);
  gemm_bf16<5, 1><<<g4096, blk, 0, stream>>>(actb, Wqkvgt, nullptr, nullptr, qb,
                                             RR, 4096, 1024);

  // 3. gk -> gkb
  gk_kernel<<<RR / 16, blk, 0, stream>>>(actb, Wgk1, Wgk2, bgk2, gkb);

  // 4+5. fused gate transforms + transposes (q~,k~ in place; khatT; vT; ebC)
  gate_trans<<<16 * 32 * 4, blk, 0, stream>>>(gkb, qb, kb, vb, ebC, khatT, vT);

  // 6. fused U + scan -> HT (UH region)
  ustate_kernel<<<16 * 16, blk, 0, stream>>>(khatT, vT, ebC, UH);

  // 7. fused intra + inter + gated rmsnorm -> ogb
  attn_fused<<<16 * NCHK, blk, 0, stream>>>(qb, kb, vT, UH, gb, rms_w, ogb);

  // 8. x1 = x + og @ Wo  (bf16 x1)
  dim3 g1024(1024 / 128, RR / 128);
  gemm_bf16<3, 1><<<g1024, blk, 0, stream>>>(ogb, Wot, nullptr, x, x1, RR, 1024, 1024);

  // 9. xn2 = LN(x1) -> actb (bf16 in)
  ln_kernel<1><<<RR, blk, 0, stream>>>(x1, ln2_w, ln2_b, actb);

  // 10. h = (leaky_relu(xn2@W1+b1))^2 -> hb
  dim3 g3072(3072 / 128, RR / 128);
  gemm_bf16<2, 1><<<g3072, blk, 0, stream>>>(actb, W1t, b1, nullptr, hb, RR, 3072, 1024);

  // 11. out = x1(bf16) + h @ W2 + b2 (f32 out)
  gemm_bf16<6, 0><<<g1024, blk, 0, stream>>>(hb, W2t, b2, x1, out, RR, 1024, 3072);
}